// Round 1
// baseline (1843.946 us; speedup 1.0000x reference)
//
#include <hip/hip_runtime.h>
#include <math.h>

// ---------------- problem constants ----------------
#define NHEAD 4
#define LRELU_S 0.2f
constexpr int N_GT = 100000, N_AG = 20000;
constexpr int E_GT = 640000, E_COMM = 320000;
constexpr int VIS = 64, COMMD = 128, MSG = 64, OUTD = 5;

// ---------------- workspace layout (float offsets) ----------------
// Phase A (GAT1): FS1@0, FD1@6.4M; Phase B overlays FS2@0 (fs1/fd1 dead).
// Phase C (comm) overlays T1/M/Y/GI/GH over everything < O_RST2.
// Peak requirement: 23,060,000 floats = 92.24 MB.
constexpr long O_FS1  = 0;           // 100000*64
constexpr long O_FD1  = 6400000;     // 20000*64
constexpr long O_FS2  = 0;           // 100000*128 (phase B)
constexpr long O_EL1  = 12800000;    // 100000*4
constexpr long O_EL2  = 13200000;    // 100000*4
constexpr long O_EBUF = 13600000;    // 640000*4
constexpr long O_RST1 = 16160000;    // 20000*64  -> h_vis1
constexpr long O_FD2  = 17440000;    // 20000*128
constexpr long O_ER1  = 20000000;    // 20000*4
constexpr long O_ER2  = 20080000;    // 20000*4
constexpr long O_EMAX = 20160000;    // 20000*4 (u32 encoded)
constexpr long O_DEN  = 20240000;    // 20000*4
constexpr long O_RST2 = 20480000;    // 20000*128 -> h (persists)
constexpr long O_DEG  = 23040000;    // 20000     (persists)
// phase C aliases (all dead regions by then)
constexpr long O_T1 = 0;             // 20000*128
constexpr long O_M  = 2560000;       // 20000*64
constexpr long O_Y  = 3840000;       // 20000*64
constexpr long O_GI = 5120000;       // 20000*384 -> ends 12.8M
constexpr long O_GH = 12800000;      // 20000*384 -> ends 20.48M (== O_RST2)

// ---------------- helpers ----------------
__device__ __forceinline__ unsigned f2ord(float f) {
    unsigned u = __float_as_uint(f);
    return (u & 0x80000000u) ? ~u : (u | 0x80000000u);
}
__device__ __forceinline__ float ord2f(unsigned u) {
    return __uint_as_float((u & 0x80000000u) ? (u ^ 0x80000000u) : ~u);
}

__global__ void fill_u32_k(unsigned* __restrict__ p, unsigned v, int n) {
    int i = blockIdx.x * blockDim.x + threadIdx.x;
    if (i < n) p[i] = v;
}

// ---------------- generic tiled GEMM: C[M,N] = act(A[M,K] @ B[K,N] + bias (+C if ACC)) ----------------
// ACT: 0 = none, 1 = relu.  K must be a multiple of 16; N a multiple of 64 here.
template <int ACT, int ACC>
__global__ __launch_bounds__(256) void gemm_k(const float* __restrict__ A,
                                              const float* __restrict__ B,
                                              const float* __restrict__ bias,
                                              float* __restrict__ C,
                                              int M, int N, int K) {
    __shared__ float As[16][68];  // pad 68 keeps 16B alignment of [kk][4*ty]
    __shared__ float Bs[16][64];
    const int tid = threadIdx.x;
    const int tx = tid & 15, ty = tid >> 4;
    const int m0 = blockIdx.y * 64, n0 = blockIdx.x * 64;
    float acc[4][4] = {};
    const int aj = tid & 15, ai0 = tid >> 4;   // A: 16 k-cols x 64 rows
    const int bc = tid & 63, bj0 = tid >> 6;   // B: 16 k-rows x 64 cols
    for (int k0 = 0; k0 < K; k0 += 16) {
#pragma unroll
        for (int it = 0; it < 4; ++it) {
            int ai = ai0 + (it << 4);
            int row = m0 + ai;
            As[aj][ai] = (row < M) ? A[(long)row * K + k0 + aj] : 0.f;
        }
#pragma unroll
        for (int it = 0; it < 4; ++it) {
            int bj = bj0 + (it << 2);
            int col = n0 + bc;
            Bs[bj][bc] = (col < N) ? B[(long)(k0 + bj) * N + col] : 0.f;
        }
        __syncthreads();
#pragma unroll
        for (int kk = 0; kk < 16; ++kk) {
            const float4 av = *reinterpret_cast<const float4*>(&As[kk][ty << 2]);
            const float4 bv = *reinterpret_cast<const float4*>(&Bs[kk][tx << 2]);
            acc[0][0] += av.x * bv.x; acc[0][1] += av.x * bv.y; acc[0][2] += av.x * bv.z; acc[0][3] += av.x * bv.w;
            acc[1][0] += av.y * bv.x; acc[1][1] += av.y * bv.y; acc[1][2] += av.y * bv.z; acc[1][3] += av.y * bv.w;
            acc[2][0] += av.z * bv.x; acc[2][1] += av.z * bv.y; acc[2][2] += av.z * bv.z; acc[2][3] += av.z * bv.w;
            acc[3][0] += av.w * bv.x; acc[3][1] += av.w * bv.y; acc[3][2] += av.w * bv.z; acc[3][3] += av.w * bv.w;
        }
        __syncthreads();
    }
#pragma unroll
    for (int i = 0; i < 4; ++i) {
        int row = m0 + (ty << 2) + i;
        if (row >= M) continue;
#pragma unroll
        for (int j = 0; j < 4; ++j) {
            int col = n0 + (tx << 2) + j;
            if (col >= N) continue;
            float v = acc[i][j];
            if (bias) v += bias[col];
            if (ACC) v += C[(long)row * N + col];
            if (ACT == 1) v = fmaxf(v, 0.f);
            C[(long)row * N + col] = v;
        }
    }
}

// el/er: out[i,h] = sum_j f[i, h*dh + j] * a[h*dh + j]
__global__ void head_reduce_k(const float* __restrict__ f, const float* __restrict__ a,
                              float* __restrict__ out, int n, int dh) {
    int i = blockIdx.x * blockDim.x + threadIdx.x;
    if (i >= n * NHEAD) return;
    int row = i >> 2, h = i & 3;
    const float* fp = f + (long)row * (NHEAD * dh) + h * dh;
    const float* ap = a + h * dh;
    float s = 0.f;
    for (int j = 0; j < dh; ++j) s += fp[j] * ap[j];
    out[i] = s;
}

__global__ void edge_max_k(const float* __restrict__ el, const float* __restrict__ er,
                           const int* __restrict__ src, const int* __restrict__ dst,
                           float* __restrict__ ebuf, unsigned* __restrict__ emax, int E) {
    int e = blockIdx.x * blockDim.x + threadIdx.x;
    if (e >= E) return;
    int s = src[e], d = dst[e];
    const float4 l = *reinterpret_cast<const float4*>(el + 4l * s);
    const float4 r = *reinterpret_cast<const float4*>(er + 4l * d);
    float v[4] = {l.x + r.x, l.y + r.y, l.z + r.z, l.w + r.w};
#pragma unroll
    for (int h = 0; h < 4; ++h) {
        float x = v[h];
        x = (x >= 0.f) ? x : LRELU_S * x;
        ebuf[4l * e + h] = x;
        atomicMax(emax + 4l * d + h, f2ord(x));
    }
}

__global__ void edge_expsum_k(const int* __restrict__ dst, const unsigned* __restrict__ emax,
                              float* __restrict__ ebuf, float* __restrict__ den, int E) {
    int e = blockIdx.x * blockDim.x + threadIdx.x;
    if (e >= E) return;
    int d = dst[e];
#pragma unroll
    for (int h = 0; h < 4; ++h) {
        float mx = ord2f(emax[4l * d + h]);
        float ex = expf(ebuf[4l * e + h] - mx);
        ebuf[4l * e + h] = ex;
        atomicAdd(den + 4l * d + h, ex);
    }
}

__global__ void edge_norm_k(const int* __restrict__ dst, const float* __restrict__ den,
                            float* __restrict__ ebuf, int E) {
    int i = blockIdx.x * blockDim.x + threadIdx.x;
    if (i >= E * NHEAD) return;
    int e = i >> 2, h = i & 3;
    ebuf[i] /= den[4l * dst[e] + h];
}

// rst[dst, c] += attn[e, h(c)] * fs[src, c];  HD = 1<<HDS channels, dh = 1<<DHS
template <int HDS, int DHS>
__global__ void edge_agg_k(const float* __restrict__ attn, const int* __restrict__ src,
                           const int* __restrict__ dst, const float* __restrict__ fs,
                           float* __restrict__ rst, int E) {
    long i = (long)blockIdx.x * blockDim.x + threadIdx.x;
    if (i >= ((long)E << HDS)) return;
    int e = (int)(i >> HDS);
    int c = (int)(i & ((1 << HDS) - 1));
    int h = c >> DHS;
    int s = src[e], d = dst[e];
    float a = attn[4l * e + h];
    atomicAdd(rst + ((long)d << HDS) + c, fs[((long)s << HDS) + c] * a);
}

__global__ void finalize1_k(float* __restrict__ rst, const float* __restrict__ feat_dst,
                            const float* __restrict__ bias, int n) {
    int i = blockIdx.x * blockDim.x + threadIdx.x;
    if (i >= n) return;
    int c = i & 63;
    rst[i] = fmaxf(rst[i] + feat_dst[i] + bias[c], 0.f);
}

__global__ void finalize2_k(float* __restrict__ rst, const float* __restrict__ hvis,
                            const float* __restrict__ feat_ag, const float* __restrict__ bias, int n) {
    int i = blockIdx.x * blockDim.x + threadIdx.x;
    if (i >= n) return;
    int row = i >> 7, c = i & 127;
    float res = (c < 64) ? hvis[(long)row * 64 + c] : feat_ag[(long)row * 64 + (c - 64)];
    rst[i] = fmaxf(rst[i] + res + bias[c], 0.f);
}

__global__ void deg_k(const int* __restrict__ cdst, float* __restrict__ deg, int E) {
    int i = blockIdx.x * blockDim.x + threadIdx.x;
    if (i < E) atomicAdd(deg + cdst[i], 1.0f);
}
__global__ void recip_k(float* __restrict__ deg, int n) {
    int i = blockIdx.x * blockDim.x + threadIdx.x;
    if (i < n) deg[i] = 1.0f / fmaxf(deg[i], 1.0f);
}

__global__ void comm_scatter_k(const float* __restrict__ m, const int* __restrict__ src,
                               const int* __restrict__ dst, const float* __restrict__ dinv,
                               float* __restrict__ y, int E) {
    long i = (long)blockIdx.x * blockDim.x + threadIdx.x;
    if (i >= (long)E * 64) return;
    int e = (int)(i >> 6), c = (int)(i & 63);
    int s = src[e], d = dst[e];
    atomicAdd(y + (long)d * 64 + c, m[(long)s * 64 + c] * dinv[d]);
}

__global__ void gru_k(const float* __restrict__ gi, const float* __restrict__ gh,
                      const float* __restrict__ hprev, float* __restrict__ hout, int n) {
    int i = blockIdx.x * blockDim.x + threadIdx.x;
    if (i >= n) return;
    int row = i >> 7, j = i & 127;
    const float* gir = gi + (long)row * 384;
    const float* ghr = gh + (long)row * 384;
    float r  = 1.f / (1.f + expf(-(gir[j] + ghr[j])));
    float zg = 1.f / (1.f + expf(-(gir[j + 128] + ghr[j + 128])));
    float nn = tanhf(gir[j + 256] + r * ghr[j + 256]);
    hout[i] = (1.f - zg) * nn + zg * hprev[i];
}

__global__ void out_k(const float* __restrict__ h, const float* __restrict__ w,
                      const float* __restrict__ b, float* __restrict__ out, int n) {
    int i = blockIdx.x * blockDim.x + threadIdx.x;
    if (i >= n) return;
    float acc[OUTD];
#pragma unroll
    for (int j = 0; j < OUTD; ++j) acc[j] = b[j];
    for (int k = 0; k < 128; ++k) {
        float v = h[(long)i * 128 + k];
#pragma unroll
        for (int j = 0; j < OUTD; ++j) acc[j] += v * w[k * OUTD + j];
    }
#pragma unroll
    for (int j = 0; j < OUTD; ++j) out[(long)i * OUTD + j] = acc[j];
}

__global__ void copy_k(const float* __restrict__ s, float* __restrict__ d, int n) {
    int i = blockIdx.x * blockDim.x + threadIdx.x;
    if (i < n) d[i] = s[i];
}

// ---------------- launcher ----------------
extern "C" void kernel_launch(void* const* d_in, const int* in_sizes, int n_in,
                              void* d_out, int out_size, void* d_ws, size_t ws_size,
                              hipStream_t stream) {
    const float* feat_gt    = (const float*)d_in[0];
    const float* feat_agent = (const float*)d_in[1];
    const float* z_in       = (const float*)d_in[2];
    const int*   gt_src     = (const int*)d_in[3];
    const int*   gt_dst     = (const int*)d_in[4];
    const int*   comm_src   = (const int*)d_in[5];
    const int*   comm_dst   = (const int*)d_in[6];
    const float* w1_src = (const float*)d_in[7];
    const float* w1_dst = (const float*)d_in[8];
    const float* a1_l   = (const float*)d_in[9];
    const float* a1_r   = (const float*)d_in[10];
    const float* b1     = (const float*)d_in[11];
    const float* w2_src = (const float*)d_in[12];
    const float* w2_dst = (const float*)d_in[13];
    const float* a2_l   = (const float*)d_in[14];
    const float* a2_r   = (const float*)d_in[15];
    const float* b2     = (const float*)d_in[16];
    const float* enc_w1 = (const float*)d_in[17];
    const float* enc_b1 = (const float*)d_in[18];
    const float* enc_w2 = (const float*)d_in[19];
    const float* enc_b2 = (const float*)d_in[20];
    const float* gw_ih  = (const float*)d_in[21];
    const float* gw_hh  = (const float*)d_in[22];
    const float* gb_ih  = (const float*)d_in[23];
    const float* gb_hh  = (const float*)d_in[24];
    const float* out_w  = (const float*)d_in[25];
    const float* out_b  = (const float*)d_in[26];

    float* ws = (float*)d_ws;
    float* out = (float*)d_out;

    auto blk = [](long n) { return dim3((unsigned)((n + 255) / 256)); };
    const dim3 T(256);

    // ---------- Phase A: GAT1 ----------
    // fs1 = feat_gt @ w1_src ; el1
    gemm_k<0, 0><<<dim3(1, (N_GT + 63) / 64), T, 0, stream>>>(feat_gt, w1_src, nullptr, ws + O_FS1, N_GT, 64, 32);
    head_reduce_k<<<blk((long)N_GT * 4), T, 0, stream>>>(ws + O_FS1, a1_l, ws + O_EL1, N_GT, 16);
    // fd1 = feat_agent @ w1_dst ; er1
    gemm_k<0, 0><<<dim3(1, (N_AG + 63) / 64), T, 0, stream>>>(feat_agent, w1_dst, nullptr, ws + O_FD1, N_AG, 64, 64);
    head_reduce_k<<<blk((long)N_AG * 4), T, 0, stream>>>(ws + O_FD1, a1_r, ws + O_ER1, N_AG, 16);
    // init emax(-inf encoded), den=0, rst1=0
    fill_u32_k<<<blk(N_AG * 4), T, 0, stream>>>((unsigned*)(ws + O_EMAX), 0x007FFFFFu, N_AG * 4);
    fill_u32_k<<<blk(N_AG * 4), T, 0, stream>>>((unsigned*)(ws + O_DEN), 0u, N_AG * 4);
    fill_u32_k<<<blk((long)N_AG * 64), T, 0, stream>>>((unsigned*)(ws + O_RST1), 0u, N_AG * 64);
    edge_max_k<<<blk(E_GT), T, 0, stream>>>(ws + O_EL1, ws + O_ER1, gt_src, gt_dst, ws + O_EBUF, (unsigned*)(ws + O_EMAX), E_GT);
    edge_expsum_k<<<blk(E_GT), T, 0, stream>>>(gt_dst, (unsigned*)(ws + O_EMAX), ws + O_EBUF, ws + O_DEN, E_GT);
    edge_norm_k<<<blk((long)E_GT * 4), T, 0, stream>>>(gt_dst, ws + O_DEN, ws + O_EBUF, E_GT);
    edge_agg_k<6, 4><<<blk((long)E_GT * 64), T, 0, stream>>>(ws + O_EBUF, gt_src, gt_dst, ws + O_FS1, ws + O_RST1, E_GT);
    finalize1_k<<<blk((long)N_AG * 64), T, 0, stream>>>(ws + O_RST1, feat_agent, b1, N_AG * 64);

    // ---------- Phase B: GAT2 ----------
    gemm_k<0, 0><<<dim3(2, (N_GT + 63) / 64), T, 0, stream>>>(feat_gt, w2_src, nullptr, ws + O_FS2, N_GT, 128, 32);
    head_reduce_k<<<blk((long)N_GT * 4), T, 0, stream>>>(ws + O_FS2, a2_l, ws + O_EL2, N_GT, 32);
    // fd2 = [h_vis1, feat_agent] @ w2_dst (split-K over the two halves)
    gemm_k<0, 0><<<dim3(2, (N_AG + 63) / 64), T, 0, stream>>>(ws + O_RST1, w2_dst, nullptr, ws + O_FD2, N_AG, 128, 64);
    gemm_k<0, 1><<<dim3(2, (N_AG + 63) / 64), T, 0, stream>>>(feat_agent, w2_dst + 64 * 128, nullptr, ws + O_FD2, N_AG, 128, 64);
    head_reduce_k<<<blk((long)N_AG * 4), T, 0, stream>>>(ws + O_FD2, a2_r, ws + O_ER2, N_AG, 32);
    fill_u32_k<<<blk(N_AG * 4), T, 0, stream>>>((unsigned*)(ws + O_EMAX), 0x007FFFFFu, N_AG * 4);
    fill_u32_k<<<blk(N_AG * 4), T, 0, stream>>>((unsigned*)(ws + O_DEN), 0u, N_AG * 4);
    fill_u32_k<<<blk((long)N_AG * 128), T, 0, stream>>>((unsigned*)(ws + O_RST2), 0u, N_AG * 128);
    edge_max_k<<<blk(E_GT), T, 0, stream>>>(ws + O_EL2, ws + O_ER2, gt_src, gt_dst, ws + O_EBUF, (unsigned*)(ws + O_EMAX), E_GT);
    edge_expsum_k<<<blk(E_GT), T, 0, stream>>>(gt_dst, (unsigned*)(ws + O_EMAX), ws + O_EBUF, ws + O_DEN, E_GT);
    edge_norm_k<<<blk((long)E_GT * 4), T, 0, stream>>>(gt_dst, ws + O_DEN, ws + O_EBUF, E_GT);
    edge_agg_k<7, 5><<<blk((long)E_GT * 128), T, 0, stream>>>(ws + O_EBUF, gt_src, gt_dst, ws + O_FS2, ws + O_RST2, E_GT);
    finalize2_k<<<blk((long)N_AG * 128), T, 0, stream>>>(ws + O_RST2, ws + O_RST1, feat_agent, b2, N_AG * 128);

    // ---------- degree (once) ----------
    fill_u32_k<<<blk(N_AG), T, 0, stream>>>((unsigned*)(ws + O_DEG), 0u, N_AG);
    deg_k<<<blk(E_COMM), T, 0, stream>>>(comm_dst, ws + O_DEG, E_COMM);
    recip_k<<<blk(N_AG), T, 0, stream>>>(ws + O_DEG, N_AG);

    // ---------- comm steps ----------
    float* h = ws + O_RST2;
    for (int step = 0; step < 2; ++step) {
        const float* zz = (step == 0) ? z_in : h;  // GRU hidden state
        // m = relu(relu(h @ enc_w1 + b1) @ enc_w2 + b2)
        gemm_k<1, 0><<<dim3(2, (N_AG + 63) / 64), T, 0, stream>>>(h, enc_w1, enc_b1, ws + O_T1, N_AG, 128, 128);
        gemm_k<1, 0><<<dim3(1, (N_AG + 63) / 64), T, 0, stream>>>(ws + O_T1, enc_w2, enc_b2, ws + O_M, N_AG, 64, 128);
        // y = segment_sum(m[src] * dinv[dst])
        fill_u32_k<<<blk((long)N_AG * 64), T, 0, stream>>>((unsigned*)(ws + O_Y), 0u, N_AG * 64);
        comm_scatter_k<<<blk((long)E_COMM * 64), T, 0, stream>>>(ws + O_M, comm_src, comm_dst, ws + O_DEG, ws + O_Y, E_COMM);
        // gi = [h,y] @ w_ih + b_ih  (split-K) ; gh = zz @ w_hh + b_hh
        gemm_k<0, 0><<<dim3(6, (N_AG + 63) / 64), T, 0, stream>>>(h, gw_ih, gb_ih, ws + O_GI, N_AG, 384, 128);
        gemm_k<0, 1><<<dim3(6, (N_AG + 63) / 64), T, 0, stream>>>(ws + O_Y, gw_ih + 128 * 384, nullptr, ws + O_GI, N_AG, 384, 64);
        gemm_k<0, 0><<<dim3(6, (N_AG + 63) / 64), T, 0, stream>>>(zz, gw_hh, gb_hh, ws + O_GH, N_AG, 384, 128);
        gru_k<<<blk((long)N_AG * 128), T, 0, stream>>>(ws + O_GI, ws + O_GH, zz, h, N_AG * 128);
    }

    // ---------- outputs ----------
    out_k<<<blk(N_AG), T, 0, stream>>>(h, out_w, out_b, out, N_AG);
    copy_k<<<blk((long)N_AG * 128), T, 0, stream>>>(h, out + (long)N_AG * OUTD, N_AG * 128);
}

// Round 2
// 921.145 us; speedup vs baseline: 2.0018x; 2.0018x over previous
//
#include <hip/hip_runtime.h>
#include <math.h>

// ---------------- problem constants ----------------
#define NHEAD 4
#define LRELU_S 0.2f
constexpr int N_GT = 100000, N_AG = 20000;
constexpr int E_GT = 640000, E_COMM = 320000;
constexpr int OUTD = 5;

// ---------------- workspace layout (float/u32 offsets, 4B units) ----------------
// Phase A/B: FS @0 (fs1 6.4M then fs2 12.8M overlaid).
// Phase C (comm) reuses [0, 17.6M) — everything there is dead by then.
constexpr long O_FS      = 0;          // up to 100000*128 = 12.8M
constexpr long O_EL1     = 12800000;   // 100000*4
constexpr long O_EL2     = 13200000;   // 100000*4
constexpr long O_RST1    = 13600000;   // 20000*64  (h_vis1)
constexpr long O_ER1     = 14880000;   // 20000*4
constexpr long O_ER2     = 14960000;   // 20000*4 -> 15.04M
constexpr long O_RST2    = 17600000;   // 20000*128 (h, persists)
constexpr long O_DINV    = 20160000;   // 20000
constexpr long O_OFFS_GT = 20180000;   // 20001 u32
constexpr long O_SRT_GT  = 20200004;   // 640000 u32
constexpr long O_OFFS_CM = 20840004;   // 20001 u32
constexpr long O_SRT_CM  = 20860008;   // 320000 u32
constexpr long O_CNT     = 21180008;   // 20000 u32
constexpr long O_CUR     = 21200008;   // 20000 u32
constexpr long O_V       = 21220008;   // VL1(128) VR1(256) VL2(128) VR2(512)
// phase C aliases (all in dead [0, 17.6M))
constexpr long O_GH = 0;               // 20000*384 -> 7.68M
constexpr long O_T1 = 7680000;         // 20000*128 -> 10.24M
constexpr long O_M  = 10240000;        // 20000*64  -> 11.52M
constexpr long O_GI = 7680000;         // 20000*384 -> 15.36M (overlays dead T1/M)
constexpr long O_Y  = 15360000;        // 20000*64  -> 16.64M

__global__ void fill_u32_k(unsigned* __restrict__ p, unsigned v, int n) {
    int i = blockIdx.x * blockDim.x + threadIdx.x;
    if (i < n) p[i] = v;
}

// ---------------- CSR build ----------------
__global__ void count_k(const int* __restrict__ dst, unsigned* __restrict__ cnt, int E) {
    int e = blockIdx.x * blockDim.x + threadIdx.x;
    if (e < E) atomicAdd(cnt + dst[e], 1u);
}

__global__ __launch_bounds__(1024) void scan_k(const unsigned* __restrict__ cnt,
                                               unsigned* __restrict__ offs,
                                               unsigned* __restrict__ cursor, int n) {
    __shared__ unsigned part[1024];
    int t = threadIdx.x;
    int chunk = (n + 1023) / 1024;
    int b = t * chunk, e = min(n, b + chunk);
    unsigned s = 0;
    for (int i = b; i < e; ++i) s += cnt[i];
    part[t] = s;
    __syncthreads();
    for (int off = 1; off < 1024; off <<= 1) {
        unsigned v = (t >= off) ? part[t - off] : 0u;
        __syncthreads();
        part[t] += v;
        __syncthreads();
    }
    unsigned run = (t > 0) ? part[t - 1] : 0u;
    for (int i = b; i < e; ++i) {
        offs[i] = run; cursor[i] = run;
        run += cnt[i];
    }
    if (t == 1023) offs[n] = run;
}

__global__ void scatter_k(const int* __restrict__ src, const int* __restrict__ dst,
                          unsigned* __restrict__ cursor, unsigned* __restrict__ sorted, int E) {
    int e = blockIdx.x * blockDim.x + threadIdx.x;
    if (e < E) {
        unsigned p = atomicAdd(cursor + dst[e], 1u);
        sorted[p] = (unsigned)src[e];
    }
}

__global__ void recip_cnt_k(const unsigned* __restrict__ cnt, float* __restrict__ dinv, int n) {
    int i = blockIdx.x * blockDim.x + threadIdx.x;
    if (i < n) dinv[i] = 1.0f / fmaxf((float)cnt[i], 1.0f);
}

// ---------------- attention projection vectors: V[k,h] = sum_j w[k, h*dh+j]*a[h,dh+j] ----------------
__global__ void make_v_k(const float* __restrict__ w, const float* __restrict__ a,
                         float* __restrict__ v, int K, int dh) {
    int i = blockIdx.x * blockDim.x + threadIdx.x;
    if (i >= K * 4) return;
    int k = i >> 2, h = i & 3;
    float s = 0.f;
    for (int j = 0; j < dh; ++j) s += w[k * (4 * dh) + h * dh + j] * a[h * dh + j];
    v[k * 4 + h] = s;
}

// out[i,h] = sum_k f[i,k] * V[k,h]
__global__ void rowvec_k(const float* __restrict__ f, const float* __restrict__ v,
                         float* __restrict__ out, int n, int K) {
    int i = blockIdx.x * blockDim.x + threadIdx.x;
    if (i >= n) return;
    float a0 = 0, a1 = 0, a2 = 0, a3 = 0;
    const float* fp = f + (long)i * K;
    for (int k = 0; k < K; ++k) {
        float x = fp[k];
        a0 += x * v[4 * k]; a1 += x * v[4 * k + 1];
        a2 += x * v[4 * k + 2]; a3 += x * v[4 * k + 3];
    }
    float4 r = {a0, a1, a2, a3};
    *reinterpret_cast<float4*>(out + 4l * i) = r;
}

// out[i,h] = sum_k f1[i,k]*V[k,h] + sum_k f2[i,k]*V[K1+k,h]
__global__ void rowvec2_k(const float* __restrict__ f1, const float* __restrict__ f2,
                          const float* __restrict__ v, float* __restrict__ out, int n, int K1, int K2) {
    int i = blockIdx.x * blockDim.x + threadIdx.x;
    if (i >= n) return;
    float a0 = 0, a1 = 0, a2 = 0, a3 = 0;
    const float* fp = f1 + (long)i * K1;
    for (int k = 0; k < K1; ++k) {
        float x = fp[k];
        a0 += x * v[4 * k]; a1 += x * v[4 * k + 1];
        a2 += x * v[4 * k + 2]; a3 += x * v[4 * k + 3];
    }
    const float* gp = f2 + (long)i * K2;
    const float* v2 = v + 4l * K1;
    for (int k = 0; k < K2; ++k) {
        float x = gp[k];
        a0 += x * v2[4 * k]; a1 += x * v2[4 * k + 1];
        a2 += x * v2[4 * k + 2]; a3 += x * v2[4 * k + 3];
    }
    float4 r = {a0, a1, a2, a3};
    *reinterpret_cast<float4*>(out + 4l * i) = r;
}

// ---------------- tiled GEMM with optional concat-K: C = act([A|A2] @ B + bias) ----------------
template <int ACT>
__global__ __launch_bounds__(256) void gemm_k(const float* __restrict__ A,
                                              const float* __restrict__ A2, int K1,
                                              const float* __restrict__ B,
                                              const float* __restrict__ bias,
                                              float* __restrict__ C,
                                              int M, int N, int K) {
    __shared__ float As[16][68];
    __shared__ float Bs[16][64];
    const int tid = threadIdx.x;
    const int tx = tid & 15, ty = tid >> 4;
    const int m0 = blockIdx.y * 64, n0 = blockIdx.x * 64;
    float acc[4][4] = {};
    const int aj = tid & 15, ai0 = tid >> 4;
    const int bc = tid & 63, bj0 = tid >> 6;
    const int K2 = K - K1;
    for (int k0 = 0; k0 < K; k0 += 16) {
        const int kg = k0 + aj;
#pragma unroll
        for (int it = 0; it < 4; ++it) {
            int ai = ai0 + (it << 4);
            int row = m0 + ai;
            float v = 0.f;
            if (row < M) {
                v = (kg < K1) ? A[(long)row * K1 + kg] : A2[(long)row * K2 + (kg - K1)];
            }
            As[aj][ai] = v;
        }
#pragma unroll
        for (int it = 0; it < 4; ++it) {
            int bj = bj0 + (it << 2);
            Bs[bj][bc] = B[(long)(k0 + bj) * N + n0 + bc];
        }
        __syncthreads();
#pragma unroll
        for (int kk = 0; kk < 16; ++kk) {
            const float4 av = *reinterpret_cast<const float4*>(&As[kk][ty << 2]);
            const float4 bv = *reinterpret_cast<const float4*>(&Bs[kk][tx << 2]);
            acc[0][0] += av.x * bv.x; acc[0][1] += av.x * bv.y; acc[0][2] += av.x * bv.z; acc[0][3] += av.x * bv.w;
            acc[1][0] += av.y * bv.x; acc[1][1] += av.y * bv.y; acc[1][2] += av.y * bv.z; acc[1][3] += av.y * bv.w;
            acc[2][0] += av.z * bv.x; acc[2][1] += av.z * bv.y; acc[2][2] += av.z * bv.z; acc[2][3] += av.z * bv.w;
            acc[3][0] += av.w * bv.x; acc[3][1] += av.w * bv.y; acc[3][2] += av.w * bv.z; acc[3][3] += av.w * bv.w;
        }
        __syncthreads();
    }
#pragma unroll
    for (int i = 0; i < 4; ++i) {
        int row = m0 + (ty << 2) + i;
        if (row >= M) continue;
#pragma unroll
        for (int j = 0; j < 4; ++j) {
            int col = n0 + (tx << 2) + j;
            float v = acc[i][j];
            if (bias) v += bias[col];
            if (ACT == 1) v = fmaxf(v, 0.f);
            C[(long)row * N + col] = v;
        }
    }
}

// ---------------- fused flash-style GAT: one wave per dst node ----------------
// CH=64: lane->channel lane, head=lane>>4 (dh=16).
// CH=128: lane->channels 2*lane,2*lane+1, head=lane>>4 (dh=32).
template <int CH>
__global__ __launch_bounds__(256) void gat_fused_k(
    const unsigned* __restrict__ offs, const unsigned* __restrict__ ssrc,
    const float* __restrict__ el, const float* __restrict__ er,
    const float* __restrict__ fs,
    const float* __restrict__ res0, const float* __restrict__ res1,
    const float* __restrict__ bias, float* __restrict__ out, int n_dst)
{
    constexpr int CPL = CH / 64;
    const int wid = threadIdx.x >> 6;
    const int lane = threadIdx.x & 63;
    const int d = blockIdx.x * 4 + wid;
    if (d >= n_dst) return;
    const int h = lane >> 4;
    const float er_h = er[4l * d + h];
    const unsigned beg = offs[d], end = offs[d + 1];
    const int c0 = lane * CPL;
    float m = -INFINITY, s = 0.f, acc0 = 0.f, acc1 = 0.f;

    for (unsigned base = beg; base < end; base += 16) {
        const unsigned na = min(16u, end - base);
        const unsigned ei = (unsigned)(lane & 15);
        const unsigned sv = ssrc[base + (ei < na ? ei : 0u)];
        float xv = el[4l * sv + h] + er_h;           // x for edge ei, head h (prefetched)
        xv = (xv >= 0.f) ? xv : LRELU_S * xv;
        // prefetch fs row of edge 0
        unsigned sc = (unsigned)__shfl((int)sv, 0);
        float2 fc;
        float f0c;
        if (CPL == 2) fc = *reinterpret_cast<const float2*>(fs + (long)sc * CH + c0);
        else          f0c = fs[(long)sc * CH + c0];
        for (unsigned j = 0; j < na; ++j) {
            const float x = __shfl(xv, (int)((h << 4) | j));
            float2 f = fc; float f0 = f0c;
            if (j + 1 < na) {
                unsigned sn = (unsigned)__shfl((int)sv, (int)(j + 1));
                if (CPL == 2) fc = *reinterpret_cast<const float2*>(fs + (long)sn * CH + c0);
                else          f0c = fs[(long)sn * CH + c0];
            }
            const float mn = fmaxf(m, x);
            const float corr = expf(m - mn);
            const float p = expf(x - mn);
            s = s * corr + p;
            if (CPL == 2) {
                acc0 = acc0 * corr + p * f.x;
                acc1 = acc1 * corr + p * f.y;
            } else {
                acc0 = acc0 * corr + p * f0;
            }
            m = mn;
        }
    }
    const float inv = (s > 0.f) ? 1.f / s : 0.f;
    if (CPL == 1) {
        float r = res0[(long)d * 64 + c0];
        out[(long)d * 64 + c0] = fmaxf(acc0 * inv + r + bias[c0], 0.f);
    } else {
        float2 r = (c0 < 64) ? *reinterpret_cast<const float2*>(res0 + (long)d * 64 + c0)
                             : *reinterpret_cast<const float2*>(res1 + (long)d * 64 + (c0 - 64));
        float2 o;
        o.x = fmaxf(acc0 * inv + r.x + bias[c0], 0.f);
        o.y = fmaxf(acc1 * inv + r.y + bias[c0 + 1], 0.f);
        *reinterpret_cast<float2*>(out + (long)d * 128 + c0) = o;
    }
}

// ---------------- comm mailbox mean: one wave per dst node ----------------
__global__ __launch_bounds__(256) void comm_gather_k(const unsigned* __restrict__ offs,
                                                     const unsigned* __restrict__ ssrc,
                                                     const float* __restrict__ m,
                                                     const float* __restrict__ dinv,
                                                     float* __restrict__ y, int n) {
    const int wid = threadIdx.x >> 6;
    const int lane = threadIdx.x & 63;
    const int d = blockIdx.x * 4 + wid;
    if (d >= n) return;
    const unsigned beg = offs[d], end = offs[d + 1];
    float acc = 0.f;
    for (unsigned base = beg; base < end; base += 64) {
        const unsigned na = min(64u, end - base);
        const unsigned sv = ssrc[base + ((unsigned)lane < na ? (unsigned)lane : 0u)];
        unsigned sc = (unsigned)__shfl((int)sv, 0);
        float fn = m[(long)sc * 64 + lane];
        for (unsigned j = 0; j < na; ++j) {
            float f = fn;
            if (j + 1 < na) {
                unsigned s2 = (unsigned)__shfl((int)sv, (int)(j + 1));
                fn = m[(long)s2 * 64 + lane];
            }
            acc += f;
        }
    }
    y[(long)d * 64 + lane] = acc * dinv[d];
}

// ---------------- GRU pointwise ----------------
__global__ void gru_k(const float* __restrict__ gi, const float* __restrict__ gh,
                      const float* __restrict__ hprev, float* __restrict__ hout, int n) {
    int i = blockIdx.x * blockDim.x + threadIdx.x;
    if (i >= n) return;
    int row = i >> 7, j = i & 127;
    const float* gir = gi + (long)row * 384;
    const float* ghr = gh + (long)row * 384;
    float r  = 1.f / (1.f + expf(-(gir[j] + ghr[j])));
    float zg = 1.f / (1.f + expf(-(gir[j + 128] + ghr[j + 128])));
    float nn = tanhf(gir[j + 256] + r * ghr[j + 256]);
    hout[i] = (1.f - zg) * nn + zg * hprev[i];
}

__global__ void out_k(const float* __restrict__ h, const float* __restrict__ w,
                      const float* __restrict__ b, float* __restrict__ out, int n) {
    int i = blockIdx.x * blockDim.x + threadIdx.x;
    if (i >= n) return;
    float acc[OUTD];
#pragma unroll
    for (int j = 0; j < OUTD; ++j) acc[j] = b[j];
    for (int k = 0; k < 128; ++k) {
        float v = h[(long)i * 128 + k];
#pragma unroll
        for (int j = 0; j < OUTD; ++j) acc[j] += v * w[k * OUTD + j];
    }
#pragma unroll
    for (int j = 0; j < OUTD; ++j) out[(long)i * OUTD + j] = acc[j];
}

__global__ void copy_k(const float* __restrict__ s, float* __restrict__ d, int n) {
    int i = blockIdx.x * blockDim.x + threadIdx.x;
    if (i < n) d[i] = s[i];
}

// ---------------- launcher ----------------
extern "C" void kernel_launch(void* const* d_in, const int* in_sizes, int n_in,
                              void* d_out, int out_size, void* d_ws, size_t ws_size,
                              hipStream_t stream) {
    const float* feat_gt    = (const float*)d_in[0];
    const float* feat_agent = (const float*)d_in[1];
    const float* z_in       = (const float*)d_in[2];
    const int*   gt_src     = (const int*)d_in[3];
    const int*   gt_dst     = (const int*)d_in[4];
    const int*   comm_src   = (const int*)d_in[5];
    const int*   comm_dst   = (const int*)d_in[6];
    const float* w1_src = (const float*)d_in[7];
    const float* w1_dst = (const float*)d_in[8];
    const float* a1_l   = (const float*)d_in[9];
    const float* a1_r   = (const float*)d_in[10];
    const float* b1     = (const float*)d_in[11];
    const float* w2_src = (const float*)d_in[12];
    const float* w2_dst = (const float*)d_in[13];
    const float* a2_l   = (const float*)d_in[14];
    const float* a2_r   = (const float*)d_in[15];
    const float* b2     = (const float*)d_in[16];
    const float* enc_w1 = (const float*)d_in[17];
    const float* enc_b1 = (const float*)d_in[18];
    const float* enc_w2 = (const float*)d_in[19];
    const float* enc_b2 = (const float*)d_in[20];
    const float* gw_ih  = (const float*)d_in[21];
    const float* gw_hh  = (const float*)d_in[22];
    const float* gb_ih  = (const float*)d_in[23];
    const float* gb_hh  = (const float*)d_in[24];
    const float* out_w  = (const float*)d_in[25];
    const float* out_b  = (const float*)d_in[26];

    float* ws = (float*)d_ws;
    unsigned* wsu = (unsigned*)d_ws;
    float* out = (float*)d_out;

    auto blk = [](long n) { return dim3((unsigned)((n + 255) / 256)); };
    const dim3 T(256);

    // ---------- CSR for gt graph ----------
    fill_u32_k<<<blk(N_AG), T, 0, stream>>>(wsu + O_CNT, 0u, N_AG);
    count_k<<<blk(E_GT), T, 0, stream>>>(gt_dst, wsu + O_CNT, E_GT);
    scan_k<<<1, 1024, 0, stream>>>(wsu + O_CNT, wsu + O_OFFS_GT, wsu + O_CUR, N_AG);
    scatter_k<<<blk(E_GT), T, 0, stream>>>(gt_src, gt_dst, wsu + O_CUR, wsu + O_SRT_GT, E_GT);
    // ---------- CSR for comm graph (+ dinv) ----------
    fill_u32_k<<<blk(N_AG), T, 0, stream>>>(wsu + O_CNT, 0u, N_AG);
    count_k<<<blk(E_COMM), T, 0, stream>>>(comm_dst, wsu + O_CNT, E_COMM);
    recip_cnt_k<<<blk(N_AG), T, 0, stream>>>(wsu + O_CNT, ws + O_DINV, N_AG);
    scan_k<<<1, 1024, 0, stream>>>(wsu + O_CNT, wsu + O_OFFS_CM, wsu + O_CUR, N_AG);
    scatter_k<<<blk(E_COMM), T, 0, stream>>>(comm_src, comm_dst, wsu + O_CUR, wsu + O_SRT_CM, E_COMM);

    // ---------- attention vectors + el/er ----------
    float* VL1 = ws + O_V, *VR1 = ws + O_V + 128, *VL2 = ws + O_V + 384, *VR2 = ws + O_V + 512;
    make_v_k<<<1, 256, 0, stream>>>(w1_src, a1_l, VL1, 32, 16);
    make_v_k<<<1, 256, 0, stream>>>(w1_dst, a1_r, VR1, 64, 16);
    make_v_k<<<1, 256, 0, stream>>>(w2_src, a2_l, VL2, 32, 32);
    make_v_k<<<dim3(2), 256, 0, stream>>>(w2_dst, a2_r, VR2, 128, 32);
    rowvec_k<<<blk(N_GT), T, 0, stream>>>(feat_gt, VL1, ws + O_EL1, N_GT, 32);
    rowvec_k<<<blk(N_GT), T, 0, stream>>>(feat_gt, VL2, ws + O_EL2, N_GT, 32);
    rowvec_k<<<blk(N_AG), T, 0, stream>>>(feat_agent, VR1, ws + O_ER1, N_AG, 64);

    // ---------- GAT1 ----------
    gemm_k<0><<<dim3(1, (N_GT + 63) / 64), T, 0, stream>>>(feat_gt, nullptr, 32, w1_src, nullptr, ws + O_FS, N_GT, 64, 32);
    gat_fused_k<64><<<dim3((N_AG + 3) / 4), T, 0, stream>>>(wsu + O_OFFS_GT, wsu + O_SRT_GT,
        ws + O_EL1, ws + O_ER1, ws + O_FS, feat_agent, nullptr, b1, ws + O_RST1, N_AG);

    // ---------- GAT2 ----------
    rowvec2_k<<<blk(N_AG), T, 0, stream>>>(ws + O_RST1, feat_agent, VR2, ws + O_ER2, N_AG, 64, 64);
    gemm_k<0><<<dim3(2, (N_GT + 63) / 64), T, 0, stream>>>(feat_gt, nullptr, 32, w2_src, nullptr, ws + O_FS, N_GT, 128, 32);
    gat_fused_k<128><<<dim3((N_AG + 3) / 4), T, 0, stream>>>(wsu + O_OFFS_GT, wsu + O_SRT_GT,
        ws + O_EL2, ws + O_ER2, ws + O_FS, ws + O_RST1, feat_agent, b2, ws + O_RST2, N_AG);

    // ---------- comm steps ----------
    float* h = ws + O_RST2;
    for (int step = 0; step < 2; ++step) {
        const float* zz = (step == 0) ? z_in : h;
        gemm_k<1><<<dim3(2, (N_AG + 63) / 64), T, 0, stream>>>(h, nullptr, 128, enc_w1, enc_b1, ws + O_T1, N_AG, 128, 128);
        gemm_k<1><<<dim3(1, (N_AG + 63) / 64), T, 0, stream>>>(ws + O_T1, nullptr, 128, enc_w2, enc_b2, ws + O_M, N_AG, 64, 128);
        comm_gather_k<<<dim3((N_AG + 3) / 4), T, 0, stream>>>(wsu + O_OFFS_CM, wsu + O_SRT_CM,
            ws + O_M, ws + O_DINV, ws + O_Y, N_AG);
        gemm_k<0><<<dim3(6, (N_AG + 63) / 64), T, 0, stream>>>(h, ws + O_Y, 128, gw_ih, gb_ih, ws + O_GI, N_AG, 384, 192);
        gemm_k<0><<<dim3(6, (N_AG + 63) / 64), T, 0, stream>>>(zz, nullptr, 128, gw_hh, gb_hh, ws + O_GH, N_AG, 384, 128);
        gru_k<<<blk((long)N_AG * 128), T, 0, stream>>>(ws + O_GI, ws + O_GH, zz, h, N_AG * 128);
    }

    // ---------- outputs ----------
    out_k<<<blk(N_AG), T, 0, stream>>>(h, out_w, out_b, out, N_AG);
    copy_k<<<blk((long)N_AG * 128), T, 0, stream>>>(h, out + (long)N_AG * OUTD, N_AG * 128);
}

// Round 3
// 727.133 us; speedup vs baseline: 2.5359x; 1.2668x over previous
//
#include <hip/hip_runtime.h>
#include <math.h>

// ---------------- problem constants ----------------
#define NHEAD 4
#define LRELU_S 0.2f
constexpr int N_GT = 100000, N_AG = 20000;
constexpr int E_GT = 640000, E_COMM = 320000;
constexpr int OUTD = 5;

// ---------------- workspace layout (float/u32 offsets, 4B units) ----------------
constexpr long O_FS      = 0;          // up to 100000*128 = 12.8M
constexpr long O_EL1     = 12800000;   // 100000*4
constexpr long O_EL2     = 13200000;   // 100000*4
constexpr long O_RST1    = 13600000;   // 20000*64  (h_vis1)
constexpr long O_ER1     = 14880000;   // 20000*4
constexpr long O_ER2     = 14960000;   // 20000*4 -> 15.04M
constexpr long O_RST2    = 17600000;   // 20000*128 (h, persists)
constexpr long O_DINV    = 20160000;   // 20000
constexpr long O_OFFS_GT = 20180000;   // 20001 u32
constexpr long O_SRT_GT  = 20200004;   // 640000 u32
constexpr long O_OFFS_CM = 20840004;   // 20001 u32
constexpr long O_SRT_CM  = 20860008;   // 320000 u32
constexpr long O_CNT     = 21180008;   // 20000 u32
constexpr long O_CUR     = 21200008;   // 20000 u32
constexpr long O_V       = 21220008;   // VL1(128) VR1(256) VL2(128) VR2(512)
constexpr long O_WB      = 21300000;   // bf16 weights, 153600 shorts = 76800 floats
// phase C aliases (dead regions by then)
constexpr long O_GH = 0;               // 20000*384 -> 7.68M
constexpr long O_T1 = 7680000;         // 20000*128 -> 10.24M
constexpr long O_M  = 10240000;        // 20000*64  -> 11.52M
constexpr long O_GI = 7680000;         // 20000*384 -> 15.36M (overlays dead T1/M)
constexpr long O_Y  = 15360000;        // 20000*64  -> 16.64M

// bf16 weight sub-offsets (in shorts, relative to O_WB)
constexpr long WB_W1 = 0;        // 64x32
constexpr long WB_W2 = 2048;     // 128x32
constexpr long WB_E1 = 6144;     // 128x128
constexpr long WB_E2 = 22528;    // 64x128
constexpr long WB_GI = 30720;    // 384x192
constexpr long WB_GH = 104448;   // 384x128 -> end 153600

using bf8     = __attribute__((ext_vector_type(8))) short;
using f32x4v  = __attribute__((ext_vector_type(4))) float;
using ushort8v= __attribute__((ext_vector_type(8))) unsigned short;

__device__ __forceinline__ unsigned short f2bf(float x) {
    unsigned u = __float_as_uint(x);
    u += 0x7FFFu + ((u >> 16) & 1u);   // round-to-nearest-even
    return (unsigned short)(u >> 16);
}

__global__ void fill_u32_k(unsigned* __restrict__ p, unsigned v, int n) {
    int i = blockIdx.x * blockDim.x + threadIdx.x;
    if (i < n) p[i] = v;
}

// ---------------- CSR build ----------------
__global__ void count_k(const int* __restrict__ dst, unsigned* __restrict__ cnt, int E) {
    int e = blockIdx.x * blockDim.x + threadIdx.x;
    if (e < E) atomicAdd(cnt + dst[e], 1u);
}

__global__ __launch_bounds__(1024) void scan_k(const unsigned* __restrict__ cnt,
                                               unsigned* __restrict__ offs,
                                               unsigned* __restrict__ cursor, int n) {
    __shared__ unsigned part[1024];
    int t = threadIdx.x;
    int chunk = (n + 1023) / 1024;
    int b = t * chunk, e = min(n, b + chunk);
    unsigned s = 0;
    for (int i = b; i < e; ++i) s += cnt[i];
    part[t] = s;
    __syncthreads();
    for (int off = 1; off < 1024; off <<= 1) {
        unsigned v = (t >= off) ? part[t - off] : 0u;
        __syncthreads();
        part[t] += v;
        __syncthreads();
    }
    unsigned run = (t > 0) ? part[t - 1] : 0u;
    for (int i = b; i < e; ++i) {
        offs[i] = run; cursor[i] = run;
        run += cnt[i];
    }
    if (t == 1023) offs[n] = run;
}

__global__ void scatter_k(const int* __restrict__ src, const int* __restrict__ dst,
                          unsigned* __restrict__ cursor, unsigned* __restrict__ sorted, int E) {
    int e = blockIdx.x * blockDim.x + threadIdx.x;
    if (e < E) {
        unsigned p = atomicAdd(cursor + dst[e], 1u);
        sorted[p] = (unsigned)src[e];
    }
}

__global__ void recip_cnt_k(const unsigned* __restrict__ cnt, float* __restrict__ dinv, int n) {
    int i = blockIdx.x * blockDim.x + threadIdx.x;
    if (i < n) dinv[i] = 1.0f / fmaxf((float)cnt[i], 1.0f);
}

// ---------------- attention projection vectors ----------------
__global__ void make_v_k(const float* __restrict__ w, const float* __restrict__ a,
                         float* __restrict__ v, int K, int dh) {
    int i = blockIdx.x * blockDim.x + threadIdx.x;
    if (i >= K * 4) return;
    int k = i >> 2, h = i & 3;
    float s = 0.f;
    for (int j = 0; j < dh; ++j) s += w[k * (4 * dh) + h * dh + j] * a[h * dh + j];
    v[k * 4 + h] = s;
}

__global__ void rowvec_k(const float* __restrict__ f, const float* __restrict__ v,
                         float* __restrict__ out, int n, int K) {
    int i = blockIdx.x * blockDim.x + threadIdx.x;
    if (i >= n) return;
    float a0 = 0, a1 = 0, a2 = 0, a3 = 0;
    const float* fp = f + (long)i * K;
    for (int k = 0; k < K; ++k) {
        float x = fp[k];
        a0 += x * v[4 * k]; a1 += x * v[4 * k + 1];
        a2 += x * v[4 * k + 2]; a3 += x * v[4 * k + 3];
    }
    float4 r = {a0, a1, a2, a3};
    *reinterpret_cast<float4*>(out + 4l * i) = r;
}

__global__ void rowvec2_k(const float* __restrict__ f1, const float* __restrict__ f2,
                          const float* __restrict__ v, float* __restrict__ out, int n, int K1, int K2) {
    int i = blockIdx.x * blockDim.x + threadIdx.x;
    if (i >= n) return;
    float a0 = 0, a1 = 0, a2 = 0, a3 = 0;
    const float* fp = f1 + (long)i * K1;
    for (int k = 0; k < K1; ++k) {
        float x = fp[k];
        a0 += x * v[4 * k]; a1 += x * v[4 * k + 1];
        a2 += x * v[4 * k + 2]; a3 += x * v[4 * k + 3];
    }
    const float* gp = f2 + (long)i * K2;
    const float* v2 = v + 4l * K1;
    for (int k = 0; k < K2; ++k) {
        float x = gp[k];
        a0 += x * v2[4 * k]; a1 += x * v2[4 * k + 1];
        a2 += x * v2[4 * k + 2]; a3 += x * v2[4 * k + 3];
    }
    float4 r = {a0, a1, a2, a3};
    *reinterpret_cast<float4*>(out + 4l * i) = r;
}

// ---------------- weight convert+transpose: Bt[n*K+k] = bf16(W[k*N+n]) ----------------
__global__ void wconv_k(const float* __restrict__ W, unsigned short* __restrict__ Bt, int K, int N) {
    int i = blockIdx.x * blockDim.x + threadIdx.x;
    if (i >= K * N) return;
    int n = i / K, k = i - n * K;
    Bt[i] = f2bf(W[(long)k * N + n]);
}

// ---------------- bf16 MFMA GEMM: C = act([A|A2] @ B + bias), B given as Bt[N][K] bf16 ----------------
// Tile 64x64, BK=32, 4 waves (2x2), wave computes 32x32 via 4x mfma_f32_16x16x32_bf16.
template <int ACT>
__global__ __launch_bounds__(256) void mgemm_k(const float* __restrict__ A,
                                               const float* __restrict__ A2, int K1,
                                               const unsigned short* __restrict__ Bt,
                                               const float* __restrict__ bias,
                                               float* __restrict__ C,
                                               int M, int N, int K) {
    __shared__ unsigned short As[64][40];   // 80B rows: b128 reads ~2-way bank alias (free)
    __shared__ unsigned short Bs[64][40];
    const int tid = threadIdx.x;
    const int lane = tid & 63, wv = tid >> 6;
    const int wm = wv & 1, wn = wv >> 1;
    const int quad = lane >> 4, l16 = lane & 15;
    const int m0 = blockIdx.y * 64, n0 = blockIdx.x * 64;
    const int K2 = K - K1;
    f32x4v acc[2][2] = {};
    const int rA = tid >> 3, cA = (tid & 7) * 4;
    const int rB = tid >> 2, cB = (tid & 3) * 8;

    for (int k0 = 0; k0 < K; k0 += 32) {
        // stage A: 64x32 fp32 -> bf16 LDS (no float4 straddles K1: both mult of 4)
#pragma unroll
        for (int half = 0; half < 2; ++half) {
            const int r = rA + half * 32;
            const int row = m0 + r;
            const int kg = k0 + cA;
            float4 v = {0.f, 0.f, 0.f, 0.f};
            if (row < M) {
                v = (kg < K1) ? *reinterpret_cast<const float4*>(A + (long)row * K1 + kg)
                              : *reinterpret_cast<const float4*>(A2 + (long)row * K2 + (kg - K1));
            }
            ushort4 b;
            b.x = f2bf(v.x); b.y = f2bf(v.y); b.z = f2bf(v.z); b.w = f2bf(v.w);
            *reinterpret_cast<ushort4*>(&As[r][cA]) = b;
        }
        // stage B: 64x32 bf16 direct copy
        *reinterpret_cast<ushort8v*>(&Bs[rB][cB]) =
            *reinterpret_cast<const ushort8v*>(Bt + (long)(n0 + rB) * K + k0 + cB);
        __syncthreads();

        const bf8 a0 = *reinterpret_cast<const bf8*>(&As[wm * 32 + l16][quad * 8]);
        const bf8 a1 = *reinterpret_cast<const bf8*>(&As[wm * 32 + 16 + l16][quad * 8]);
        const bf8 b0 = *reinterpret_cast<const bf8*>(&Bs[wn * 32 + l16][quad * 8]);
        const bf8 b1 = *reinterpret_cast<const bf8*>(&Bs[wn * 32 + 16 + l16][quad * 8]);
        acc[0][0] = __builtin_amdgcn_mfma_f32_16x16x32_bf16(a0, b0, acc[0][0], 0, 0, 0);
        acc[0][1] = __builtin_amdgcn_mfma_f32_16x16x32_bf16(a0, b1, acc[0][1], 0, 0, 0);
        acc[1][0] = __builtin_amdgcn_mfma_f32_16x16x32_bf16(a1, b0, acc[1][0], 0, 0, 0);
        acc[1][1] = __builtin_amdgcn_mfma_f32_16x16x32_bf16(a1, b1, acc[1][1], 0, 0, 0);
        __syncthreads();
    }

#pragma unroll
    for (int mt = 0; mt < 2; ++mt)
#pragma unroll
        for (int nt = 0; nt < 2; ++nt)
#pragma unroll
            for (int r = 0; r < 4; ++r) {
                const int row = m0 + wm * 32 + mt * 16 + quad * 4 + r;
                const int col = n0 + wn * 32 + nt * 16 + l16;
                if (row < M) {
                    float v = acc[mt][nt][r];
                    if (bias) v += bias[col];
                    if (ACT) v = fmaxf(v, 0.f);
                    C[(long)row * N + col] = v;
                }
            }
}

// ---------------- fused flash-style GAT: one wave per dst node ----------------
template <int CH>
__global__ __launch_bounds__(256) void gat_fused_k(
    const unsigned* __restrict__ offs, const unsigned* __restrict__ ssrc,
    const float* __restrict__ el, const float* __restrict__ er,
    const float* __restrict__ fs,
    const float* __restrict__ res0, const float* __restrict__ res1,
    const float* __restrict__ bias, float* __restrict__ out, int n_dst)
{
    constexpr int CPL = CH / 64;
    const int wid = threadIdx.x >> 6;
    const int lane = threadIdx.x & 63;
    const int d = blockIdx.x * 4 + wid;
    if (d >= n_dst) return;
    const int h = lane >> 4;
    const float er_h = er[4l * d + h];
    const unsigned beg = offs[d], end = offs[d + 1];
    const int c0 = lane * CPL;
    float m = -INFINITY, s = 0.f, acc0 = 0.f, acc1 = 0.f;

    for (unsigned base = beg; base < end; base += 16) {
        const unsigned na = min(16u, end - base);
        const unsigned ei = (unsigned)(lane & 15);
        const unsigned sv = ssrc[base + (ei < na ? ei : 0u)];
        float xv = el[4l * sv + h] + er_h;
        xv = (xv >= 0.f) ? xv : LRELU_S * xv;
        unsigned sc = (unsigned)__shfl((int)sv, 0);
        float2 fc;
        float f0c;
        if (CPL == 2) fc = *reinterpret_cast<const float2*>(fs + (long)sc * CH + c0);
        else          f0c = fs[(long)sc * CH + c0];
        for (unsigned j = 0; j < na; ++j) {
            const float x = __shfl(xv, (int)((h << 4) | j));
            float2 f = fc; float f0 = f0c;
            if (j + 1 < na) {
                unsigned sn = (unsigned)__shfl((int)sv, (int)(j + 1));
                if (CPL == 2) fc = *reinterpret_cast<const float2*>(fs + (long)sn * CH + c0);
                else          f0c = fs[(long)sn * CH + c0];
            }
            const float mn = fmaxf(m, x);
            const float corr = expf(m - mn);
            const float p = expf(x - mn);
            s = s * corr + p;
            if (CPL == 2) {
                acc0 = acc0 * corr + p * f.x;
                acc1 = acc1 * corr + p * f.y;
            } else {
                acc0 = acc0 * corr + p * f0;
            }
            m = mn;
        }
    }
    const float inv = (s > 0.f) ? 1.f / s : 0.f;
    if (CPL == 1) {
        float r = res0[(long)d * 64 + c0];
        out[(long)d * 64 + c0] = fmaxf(acc0 * inv + r + bias[c0], 0.f);
    } else {
        float2 r = (c0 < 64) ? *reinterpret_cast<const float2*>(res0 + (long)d * 64 + c0)
                             : *reinterpret_cast<const float2*>(res1 + (long)d * 64 + (c0 - 64));
        float2 o;
        o.x = fmaxf(acc0 * inv + r.x + bias[c0], 0.f);
        o.y = fmaxf(acc1 * inv + r.y + bias[c0 + 1], 0.f);
        *reinterpret_cast<float2*>(out + (long)d * 128 + c0) = o;
    }
}

// ---------------- comm mailbox mean: one wave per dst node ----------------
__global__ __launch_bounds__(256) void comm_gather_k(const unsigned* __restrict__ offs,
                                                     const unsigned* __restrict__ ssrc,
                                                     const float* __restrict__ m,
                                                     const float* __restrict__ dinv,
                                                     float* __restrict__ y, int n) {
    const int wid = threadIdx.x >> 6;
    const int lane = threadIdx.x & 63;
    const int d = blockIdx.x * 4 + wid;
    if (d >= n) return;
    const unsigned beg = offs[d], end = offs[d + 1];
    float acc = 0.f;
    for (unsigned base = beg; base < end; base += 64) {
        const unsigned na = min(64u, end - base);
        const unsigned sv = ssrc[base + ((unsigned)lane < na ? (unsigned)lane : 0u)];
        unsigned sc = (unsigned)__shfl((int)sv, 0);
        float fn = m[(long)sc * 64 + lane];
        for (unsigned j = 0; j < na; ++j) {
            float f = fn;
            if (j + 1 < na) {
                unsigned s2 = (unsigned)__shfl((int)sv, (int)(j + 1));
                fn = m[(long)s2 * 64 + lane];
            }
            acc += f;
        }
    }
    y[(long)d * 64 + lane] = acc * dinv[d];
}

// ---------------- GRU pointwise ----------------
__global__ void gru_k(const float* __restrict__ gi, const float* __restrict__ gh,
                      const float* __restrict__ hprev, float* __restrict__ hout, int n) {
    int i = blockIdx.x * blockDim.x + threadIdx.x;
    if (i >= n) return;
    int row = i >> 7, j = i & 127;
    const float* gir = gi + (long)row * 384;
    const float* ghr = gh + (long)row * 384;
    float r  = 1.f / (1.f + expf(-(gir[j] + ghr[j])));
    float zg = 1.f / (1.f + expf(-(gir[j + 128] + ghr[j + 128])));
    float nn = tanhf(gir[j + 256] + r * ghr[j + 256]);
    hout[i] = (1.f - zg) * nn + zg * hprev[i];
}

__global__ void out_k(const float* __restrict__ h, const float* __restrict__ w,
                      const float* __restrict__ b, float* __restrict__ out, int n) {
    int i = blockIdx.x * blockDim.x + threadIdx.x;
    if (i >= n) return;
    float acc[OUTD];
#pragma unroll
    for (int j = 0; j < OUTD; ++j) acc[j] = b[j];
    for (int k = 0; k < 128; ++k) {
        float v = h[(long)i * 128 + k];
#pragma unroll
        for (int j = 0; j < OUTD; ++j) acc[j] += v * w[k * OUTD + j];
    }
#pragma unroll
    for (int j = 0; j < OUTD; ++j) out[(long)i * OUTD + j] = acc[j];
}

__global__ void copy_k(const float* __restrict__ s, float* __restrict__ d, int n) {
    int i = blockIdx.x * blockDim.x + threadIdx.x;
    if (i < n) d[i] = s[i];
}

// ---------------- launcher ----------------
extern "C" void kernel_launch(void* const* d_in, const int* in_sizes, int n_in,
                              void* d_out, int out_size, void* d_ws, size_t ws_size,
                              hipStream_t stream) {
    const float* feat_gt    = (const float*)d_in[0];
    const float* feat_agent = (const float*)d_in[1];
    const float* z_in       = (const float*)d_in[2];
    const int*   gt_src     = (const int*)d_in[3];
    const int*   gt_dst     = (const int*)d_in[4];
    const int*   comm_src   = (const int*)d_in[5];
    const int*   comm_dst   = (const int*)d_in[6];
    const float* w1_src = (const float*)d_in[7];
    const float* w1_dst = (const float*)d_in[8];
    const float* a1_l   = (const float*)d_in[9];
    const float* a1_r   = (const float*)d_in[10];
    const float* b1     = (const float*)d_in[11];
    const float* w2_src = (const float*)d_in[12];
    const float* w2_dst = (const float*)d_in[13];
    const float* a2_l   = (const float*)d_in[14];
    const float* a2_r   = (const float*)d_in[15];
    const float* b2     = (const float*)d_in[16];
    const float* enc_w1 = (const float*)d_in[17];
    const float* enc_b1 = (const float*)d_in[18];
    const float* enc_w2 = (const float*)d_in[19];
    const float* enc_b2 = (const float*)d_in[20];
    const float* gw_ih  = (const float*)d_in[21];
    const float* gw_hh  = (const float*)d_in[22];
    const float* gb_ih  = (const float*)d_in[23];
    const float* gb_hh  = (const float*)d_in[24];
    const float* out_w  = (const float*)d_in[25];
    const float* out_b  = (const float*)d_in[26];

    float* ws = (float*)d_ws;
    unsigned* wsu = (unsigned*)d_ws;
    unsigned short* wb = (unsigned short*)(ws + O_WB);
    float* out = (float*)d_out;

    auto blk = [](long n) { return dim3((unsigned)((n + 255) / 256)); };
    const dim3 T(256);

    // ---------- CSR for gt graph ----------
    fill_u32_k<<<blk(N_AG), T, 0, stream>>>(wsu + O_CNT, 0u, N_AG);
    count_k<<<blk(E_GT), T, 0, stream>>>(gt_dst, wsu + O_CNT, E_GT);
    scan_k<<<1, 1024, 0, stream>>>(wsu + O_CNT, wsu + O_OFFS_GT, wsu + O_CUR, N_AG);
    scatter_k<<<blk(E_GT), T, 0, stream>>>(gt_src, gt_dst, wsu + O_CUR, wsu + O_SRT_GT, E_GT);
    // ---------- CSR for comm graph (+ dinv) ----------
    fill_u32_k<<<blk(N_AG), T, 0, stream>>>(wsu + O_CNT, 0u, N_AG);
    count_k<<<blk(E_COMM), T, 0, stream>>>(comm_dst, wsu + O_CNT, E_COMM);
    recip_cnt_k<<<blk(N_AG), T, 0, stream>>>(wsu + O_CNT, ws + O_DINV, N_AG);
    scan_k<<<1, 1024, 0, stream>>>(wsu + O_CNT, wsu + O_OFFS_CM, wsu + O_CUR, N_AG);
    scatter_k<<<blk(E_COMM), T, 0, stream>>>(comm_src, comm_dst, wsu + O_CUR, wsu + O_SRT_CM, E_COMM);

    // ---------- bf16 weight transposes ----------
    wconv_k<<<blk(64 * 32), T, 0, stream>>>(w1_src, wb + WB_W1, 32, 64);
    wconv_k<<<blk(128 * 32), T, 0, stream>>>(w2_src, wb + WB_W2, 32, 128);
    wconv_k<<<blk(128 * 128), T, 0, stream>>>(enc_w1, wb + WB_E1, 128, 128);
    wconv_k<<<blk(64 * 128), T, 0, stream>>>(enc_w2, wb + WB_E2, 128, 64);
    wconv_k<<<blk(384 * 192), T, 0, stream>>>(gw_ih, wb + WB_GI, 192, 384);
    wconv_k<<<blk(384 * 128), T, 0, stream>>>(gw_hh, wb + WB_GH, 128, 384);

    // ---------- attention vectors + el/er ----------
    float* VL1 = ws + O_V, *VR1 = ws + O_V + 128, *VL2 = ws + O_V + 384, *VR2 = ws + O_V + 512;
    make_v_k<<<1, 256, 0, stream>>>(w1_src, a1_l, VL1, 32, 16);
    make_v_k<<<1, 256, 0, stream>>>(w1_dst, a1_r, VR1, 64, 16);
    make_v_k<<<1, 256, 0, stream>>>(w2_src, a2_l, VL2, 32, 32);
    make_v_k<<<dim3(2), 256, 0, stream>>>(w2_dst, a2_r, VR2, 128, 32);
    rowvec_k<<<blk(N_GT), T, 0, stream>>>(feat_gt, VL1, ws + O_EL1, N_GT, 32);
    rowvec_k<<<blk(N_GT), T, 0, stream>>>(feat_gt, VL2, ws + O_EL2, N_GT, 32);
    rowvec_k<<<blk(N_AG), T, 0, stream>>>(feat_agent, VR1, ws + O_ER1, N_AG, 64);

    const int MB_GT = (N_GT + 63) / 64, MB_AG = (N_AG + 63) / 64;

    // ---------- GAT1 ----------
    mgemm_k<0><<<dim3(1, MB_GT), T, 0, stream>>>(feat_gt, nullptr, 32, wb + WB_W1, nullptr, ws + O_FS, N_GT, 64, 32);
    gat_fused_k<64><<<dim3((N_AG + 3) / 4), T, 0, stream>>>(wsu + O_OFFS_GT, wsu + O_SRT_GT,
        ws + O_EL1, ws + O_ER1, ws + O_FS, feat_agent, nullptr, b1, ws + O_RST1, N_AG);

    // ---------- GAT2 ----------
    rowvec2_k<<<blk(N_AG), T, 0, stream>>>(ws + O_RST1, feat_agent, VR2, ws + O_ER2, N_AG, 64, 64);
    mgemm_k<0><<<dim3(2, MB_GT), T, 0, stream>>>(feat_gt, nullptr, 32, wb + WB_W2, nullptr, ws + O_FS, N_GT, 128, 32);
    gat_fused_k<128><<<dim3((N_AG + 3) / 4), T, 0, stream>>>(wsu + O_OFFS_GT, wsu + O_SRT_GT,
        ws + O_EL2, ws + O_ER2, ws + O_FS, ws + O_RST1, feat_agent, b2, ws + O_RST2, N_AG);

    // ---------- comm steps ----------
    float* h = ws + O_RST2;
    for (int step = 0; step < 2; ++step) {
        const float* zz = (step == 0) ? z_in : h;
        mgemm_k<1><<<dim3(2, MB_AG), T, 0, stream>>>(h, nullptr, 128, wb + WB_E1, enc_b1, ws + O_T1, N_AG, 128, 128);
        mgemm_k<1><<<dim3(1, MB_AG), T, 0, stream>>>(ws + O_T1, nullptr, 128, wb + WB_E2, enc_b2, ws + O_M, N_AG, 64, 128);
        comm_gather_k<<<dim3((N_AG + 3) / 4), T, 0, stream>>>(wsu + O_OFFS_CM, wsu + O_SRT_CM,
            ws + O_M, ws + O_DINV, ws + O_Y, N_AG);
        mgemm_k<0><<<dim3(6, MB_AG), T, 0, stream>>>(h, ws + O_Y, 128, wb + WB_GI, gb_ih, ws + O_GI, N_AG, 384, 192);
        mgemm_k<0><<<dim3(6, MB_AG), T, 0, stream>>>(zz, nullptr, 128, wb + WB_GH, gb_hh, ws + O_GH, N_AG, 384, 128);
        gru_k<<<blk((long)N_AG * 128), T, 0, stream>>>(ws + O_GI, ws + O_GH, zz, h, N_AG * 128);
    }

    // ---------- outputs ----------
    out_k<<<blk(N_AG), T, 0, stream>>>(h, out_w, out_b, out, N_AG);
    copy_k<<<blk((long)N_AG * 128), T, 0, stream>>>(h, out + (long)N_AG * OUTD, N_AG * 128);
}

// Round 4
// 668.787 us; speedup vs baseline: 2.7571x; 1.0872x over previous
//
#include <hip/hip_runtime.h>
#include <math.h>

// ---------------- problem constants ----------------
#define NHEAD 4
#define LRELU_S 0.2f
constexpr int N_GT = 100000, N_AG = 20000;
constexpr int E_GT = 640000, E_COMM = 320000;
constexpr int OUTD = 5;

// ---------------- workspace layout (float/u32 units of 4B) ----------------
constexpr long O_FSB1    = 0;          // N_GT*64 bf16 = 3.2M units
constexpr long O_FSB2    = 3200000;    // N_GT*128 bf16 = 6.4M units -> 9.6M
constexpr long O_EL1     = 12800000;   // 100000*4
constexpr long O_EL2     = 13200000;   // 100000*4
constexpr long O_RST1    = 13600000;   // 20000*64  (h_vis1)
constexpr long O_ER1     = 14880000;   // 20000*4
constexpr long O_ER2     = 14960000;   // 20000*4 -> 15.04M
constexpr long O_RST2    = 17600000;   // 20000*128 (h, persists)
constexpr long O_DINV    = 20160000;   // 20000
constexpr long O_OFFS_GT = 20180000;   // 20001 u32
constexpr long O_SRT_GT  = 20200004;   // 640000 u32
constexpr long O_OFFS_CM = 20840004;   // 20001 u32
constexpr long O_SRT_CM  = 20860008;   // 320000 u32
constexpr long O_CNT     = 21180008;   // 20000 u32
constexpr long O_CUR     = 21200008;   // 20000 u32
constexpr long O_V       = 21220008;   // VL1(128) VR1(256) VL2(128) VR2(512)
constexpr long O_WB      = 21300000;   // bf16 weights (shorts)
// phase C aliases (fsb1/fsb2/EL dead by then)
constexpr long O_GH = 0;               // 20000*384 bf16 = 3.84M units
constexpr long O_T1 = 7680000;         // 20000*128 fp32 -> 10.24M
constexpr long O_M  = 10240000;        // 20000*64 bf16 = 0.32M units
constexpr long O_GI = 7680000;         // 20000*384 bf16 -> 11.52M (overlays dead T1)
constexpr long O_Y  = 15360000;        // 20000*64 fp32 -> 16.64M

// bf16 weight sub-offsets (shorts, relative to O_WB)
constexpr long WB_FS = 0;        // combined [w1|w2] transposed: 192x32
constexpr long WB_E1 = 6144;     // 128x128
constexpr long WB_E2 = 22528;    // 64x128
constexpr long WB_GI = 30720;    // 384x192
constexpr long WB_GH = 104448;   // 384x128 -> end 153600

using bf8      = __attribute__((ext_vector_type(8))) short;
using f32x4v   = __attribute__((ext_vector_type(4))) float;
using ushort8v = __attribute__((ext_vector_type(8))) unsigned short;

__device__ __forceinline__ unsigned short f2bf(float x) {
    unsigned u = __float_as_uint(x);
    u += 0x7FFFu + ((u >> 16) & 1u);
    return (unsigned short)(u >> 16);
}
__device__ __forceinline__ float bf2f(unsigned short u) {
    return __uint_as_float(((unsigned)u) << 16);
}

__global__ void fill_u32_k(unsigned* __restrict__ p, unsigned v, int n) {
    int i = blockIdx.x * blockDim.x + threadIdx.x;
    if (i < n) p[i] = v;
}

// ---------------- CSR build ----------------
__global__ void count_k(const int* __restrict__ dst, unsigned* __restrict__ cnt, int E) {
    int e = blockIdx.x * blockDim.x + threadIdx.x;
    if (e < E) atomicAdd(cnt + dst[e], 1u);
}

__global__ __launch_bounds__(1024) void scan_k(const unsigned* __restrict__ cnt,
                                               unsigned* __restrict__ offs,
                                               unsigned* __restrict__ cursor, int n) {
    __shared__ unsigned part[1024];
    int t = threadIdx.x;
    int chunk = (n + 1023) / 1024;
    int b = t * chunk, e = min(n, b + chunk);
    unsigned s = 0;
    for (int i = b; i < e; ++i) s += cnt[i];
    part[t] = s;
    __syncthreads();
    for (int off = 1; off < 1024; off <<= 1) {
        unsigned v = (t >= off) ? part[t - off] : 0u;
        __syncthreads();
        part[t] += v;
        __syncthreads();
    }
    unsigned run = (t > 0) ? part[t - 1] : 0u;
    for (int i = b; i < e; ++i) {
        offs[i] = run; cursor[i] = run;
        run += cnt[i];
    }
    if (t == 1023) offs[n] = run;
}

__global__ void scatter_k(const int* __restrict__ src, const int* __restrict__ dst,
                          unsigned* __restrict__ cursor, unsigned* __restrict__ sorted, int E) {
    int e = blockIdx.x * blockDim.x + threadIdx.x;
    if (e < E) {
        unsigned p = atomicAdd(cursor + dst[e], 1u);
        sorted[p] = (unsigned)src[e];
    }
}

__global__ void recip_cnt_k(const unsigned* __restrict__ cnt, float* __restrict__ dinv, int n) {
    int i = blockIdx.x * blockDim.x + threadIdx.x;
    if (i < n) dinv[i] = 1.0f / fmaxf((float)cnt[i], 1.0f);
}

// ---------------- attention projection vectors ----------------
__global__ void make_v_k(const float* __restrict__ w, const float* __restrict__ a,
                         float* __restrict__ v, int K, int dh) {
    int i = blockIdx.x * blockDim.x + threadIdx.x;
    if (i >= K * 4) return;
    int k = i >> 2, h = i & 3;
    float s = 0.f;
    for (int j = 0; j < dh; ++j) s += w[k * (4 * dh) + h * dh + j] * a[h * dh + j];
    v[k * 4 + h] = s;
}

// el1[i,:], el2[i,:] from one pass over feat_gt (K=32)
__global__ void rowvec8_k(const float* __restrict__ f, const float* __restrict__ v1,
                          const float* __restrict__ v2, float* __restrict__ o1,
                          float* __restrict__ o2, int n) {
    int i = blockIdx.x * blockDim.x + threadIdx.x;
    if (i >= n) return;
    float a[8] = {};
    const float* fp = f + (long)i * 32;
    for (int k = 0; k < 32; ++k) {
        float x = fp[k];
#pragma unroll
        for (int j = 0; j < 4; ++j) a[j] += x * v1[4 * k + j];
#pragma unroll
        for (int j = 0; j < 4; ++j) a[4 + j] += x * v2[4 * k + j];
    }
    *reinterpret_cast<float4*>(o1 + 4l * i) = {a[0], a[1], a[2], a[3]};
    *reinterpret_cast<float4*>(o2 + 4l * i) = {a[4], a[5], a[6], a[7]};
}

__global__ void rowvec_k(const float* __restrict__ f, const float* __restrict__ v,
                         float* __restrict__ out, int n, int K) {
    int i = blockIdx.x * blockDim.x + threadIdx.x;
    if (i >= n) return;
    float a0 = 0, a1 = 0, a2 = 0, a3 = 0;
    const float* fp = f + (long)i * K;
    for (int k = 0; k < K; ++k) {
        float x = fp[k];
        a0 += x * v[4 * k]; a1 += x * v[4 * k + 1];
        a2 += x * v[4 * k + 2]; a3 += x * v[4 * k + 3];
    }
    float4 r = {a0, a1, a2, a3};
    *reinterpret_cast<float4*>(out + 4l * i) = r;
}

__global__ void rowvec2_k(const float* __restrict__ f1, const float* __restrict__ f2,
                          const float* __restrict__ v, float* __restrict__ out, int n, int K1, int K2) {
    int i = blockIdx.x * blockDim.x + threadIdx.x;
    if (i >= n) return;
    float a0 = 0, a1 = 0, a2 = 0, a3 = 0;
    const float* fp = f1 + (long)i * K1;
    for (int k = 0; k < K1; ++k) {
        float x = fp[k];
        a0 += x * v[4 * k]; a1 += x * v[4 * k + 1];
        a2 += x * v[4 * k + 2]; a3 += x * v[4 * k + 3];
    }
    const float* gp = f2 + (long)i * K2;
    const float* v2 = v + 4l * K1;
    for (int k = 0; k < K2; ++k) {
        float x = gp[k];
        a0 += x * v2[4 * k]; a1 += x * v2[4 * k + 1];
        a2 += x * v2[4 * k + 2]; a3 += x * v2[4 * k + 3];
    }
    float4 r = {a0, a1, a2, a3};
    *reinterpret_cast<float4*>(out + 4l * i) = r;
}

// ---------------- weight convert+transpose: Bt[n*K+k] = bf16(W[k*N+n]) ----------------
__global__ void wconv_k(const float* __restrict__ W, unsigned short* __restrict__ Bt, int K, int N) {
    int i = blockIdx.x * blockDim.x + threadIdx.x;
    if (i >= K * N) return;
    int n = i / K, k = i - n * K;
    Bt[i] = f2bf(W[(long)k * N + n]);
}

// ---------------- bf16 MFMA GEMM: C = act([A|A2] @ B + bias), Bt[N][K] bf16, out fp32 or bf16 ----------------
template <int ACT, int OB>
__global__ __launch_bounds__(256) void mgemm_k(const float* __restrict__ A,
                                               const float* __restrict__ A2, int K1,
                                               const unsigned short* __restrict__ Bt,
                                               const float* __restrict__ bias,
                                               void* __restrict__ Cv,
                                               int M, int N, int K) {
    __shared__ unsigned short As[64][40];
    __shared__ unsigned short Bs[64][40];
    const int tid = threadIdx.x;
    const int lane = tid & 63, wv = tid >> 6;
    const int wm = wv & 1, wn = wv >> 1;
    const int quad = lane >> 4, l16 = lane & 15;
    const int m0 = blockIdx.y * 64, n0 = blockIdx.x * 64;
    const int K2 = K - K1;
    f32x4v acc[2][2] = {};
    const int rA = tid >> 3, cA = (tid & 7) * 4;
    const int rB = tid >> 2, cB = (tid & 3) * 8;

    for (int k0 = 0; k0 < K; k0 += 32) {
#pragma unroll
        for (int half = 0; half < 2; ++half) {
            const int r = rA + half * 32;
            const int row = m0 + r;
            const int kg = k0 + cA;
            float4 v = {0.f, 0.f, 0.f, 0.f};
            if (row < M) {
                v = (kg < K1) ? *reinterpret_cast<const float4*>(A + (long)row * K1 + kg)
                              : *reinterpret_cast<const float4*>(A2 + (long)row * K2 + (kg - K1));
            }
            ushort4 b;
            b.x = f2bf(v.x); b.y = f2bf(v.y); b.z = f2bf(v.z); b.w = f2bf(v.w);
            *reinterpret_cast<ushort4*>(&As[r][cA]) = b;
        }
        *reinterpret_cast<ushort8v*>(&Bs[rB][cB]) =
            *reinterpret_cast<const ushort8v*>(Bt + (long)(n0 + rB) * K + k0 + cB);
        __syncthreads();

        const bf8 a0 = *reinterpret_cast<const bf8*>(&As[wm * 32 + l16][quad * 8]);
        const bf8 a1 = *reinterpret_cast<const bf8*>(&As[wm * 32 + 16 + l16][quad * 8]);
        const bf8 b0 = *reinterpret_cast<const bf8*>(&Bs[wn * 32 + l16][quad * 8]);
        const bf8 b1 = *reinterpret_cast<const bf8*>(&Bs[wn * 32 + 16 + l16][quad * 8]);
        acc[0][0] = __builtin_amdgcn_mfma_f32_16x16x32_bf16(a0, b0, acc[0][0], 0, 0, 0);
        acc[0][1] = __builtin_amdgcn_mfma_f32_16x16x32_bf16(a0, b1, acc[0][1], 0, 0, 0);
        acc[1][0] = __builtin_amdgcn_mfma_f32_16x16x32_bf16(a1, b0, acc[1][0], 0, 0, 0);
        acc[1][1] = __builtin_amdgcn_mfma_f32_16x16x32_bf16(a1, b1, acc[1][1], 0, 0, 0);
        __syncthreads();
    }

#pragma unroll
    for (int mt = 0; mt < 2; ++mt)
#pragma unroll
        for (int nt = 0; nt < 2; ++nt)
#pragma unroll
            for (int r = 0; r < 4; ++r) {
                const int row = m0 + wm * 32 + mt * 16 + quad * 4 + r;
                const int col = n0 + wn * 32 + nt * 16 + l16;
                if (row < M) {
                    float v = acc[mt][nt][r];
                    if (bias) v += bias[col];
                    if (ACT) v = fmaxf(v, 0.f);
                    if (OB) ((unsigned short*)Cv)[(long)row * N + col] = f2bf(v);
                    else    ((float*)Cv)[(long)row * N + col] = v;
                }
            }
}

// ---------------- fused fs1+fs2 producer: [fs1|fs2] = feat_gt @ [w1|w2], bf16 out ----------------
__global__ __launch_bounds__(256) void fs_gemm_k(const float* __restrict__ A,
                                                 const unsigned short* __restrict__ Btc,
                                                 unsigned short* __restrict__ fsb1,
                                                 unsigned short* __restrict__ fsb2, int M) {
    __shared__ unsigned short As[64][40];
    __shared__ unsigned short Bs[64][40];
    const int tid = threadIdx.x;
    const int lane = tid & 63, wv = tid >> 6;
    const int wm = wv & 1, wn = wv >> 1;
    const int quad = lane >> 4, l16 = lane & 15;
    const int m0 = blockIdx.y * 64, n0 = blockIdx.x * 64;
    f32x4v acc[2][2] = {};
    const int rA = tid >> 3, cA = (tid & 7) * 4;
    const int rB = tid >> 2, cB = (tid & 3) * 8;

#pragma unroll
    for (int half = 0; half < 2; ++half) {
        const int r = rA + half * 32;
        const int row = m0 + r;
        float4 v = {0.f, 0.f, 0.f, 0.f};
        if (row < M) v = *reinterpret_cast<const float4*>(A + (long)row * 32 + cA);
        ushort4 b;
        b.x = f2bf(v.x); b.y = f2bf(v.y); b.z = f2bf(v.z); b.w = f2bf(v.w);
        *reinterpret_cast<ushort4*>(&As[r][cA]) = b;
    }
    *reinterpret_cast<ushort8v*>(&Bs[rB][cB]) =
        *reinterpret_cast<const ushort8v*>(Btc + (long)(n0 + rB) * 32 + cB);
    __syncthreads();

    const bf8 a0 = *reinterpret_cast<const bf8*>(&As[wm * 32 + l16][quad * 8]);
    const bf8 a1 = *reinterpret_cast<const bf8*>(&As[wm * 32 + 16 + l16][quad * 8]);
    const bf8 b0 = *reinterpret_cast<const bf8*>(&Bs[wn * 32 + l16][quad * 8]);
    const bf8 b1 = *reinterpret_cast<const bf8*>(&Bs[wn * 32 + 16 + l16][quad * 8]);
    acc[0][0] = __builtin_amdgcn_mfma_f32_16x16x32_bf16(a0, b0, acc[0][0], 0, 0, 0);
    acc[0][1] = __builtin_amdgcn_mfma_f32_16x16x32_bf16(a0, b1, acc[0][1], 0, 0, 0);
    acc[1][0] = __builtin_amdgcn_mfma_f32_16x16x32_bf16(a1, b0, acc[1][0], 0, 0, 0);
    acc[1][1] = __builtin_amdgcn_mfma_f32_16x16x32_bf16(a1, b1, acc[1][1], 0, 0, 0);

#pragma unroll
    for (int mt = 0; mt < 2; ++mt)
#pragma unroll
        for (int nt = 0; nt < 2; ++nt)
#pragma unroll
            for (int r = 0; r < 4; ++r) {
                const int row = m0 + wm * 32 + mt * 16 + quad * 4 + r;
                const int col = n0 + wn * 32 + nt * 16 + l16;
                if (row < M) {
                    unsigned short v16 = f2bf(acc[mt][nt][r]);
                    if (col < 64) fsb1[(long)row * 64 + col] = v16;
                    else          fsb2[(long)row * 128 + (col - 64)] = v16;
                }
            }
}

// ---------------- fused flash GAT v2: chunked online softmax, bf16 fs ----------------
template <int CH>
__global__ __launch_bounds__(256) void gat_fused_k(
    const unsigned* __restrict__ offs, const unsigned* __restrict__ ssrc,
    const float* __restrict__ el, const float* __restrict__ er,
    const unsigned short* __restrict__ fsb,
    const float* __restrict__ res0, const float* __restrict__ res1,
    const float* __restrict__ bias, float* __restrict__ out, int n_dst)
{
    constexpr int CPL = CH / 64;
    const int wid = threadIdx.x >> 6;
    const int lane = threadIdx.x & 63;
    const int d = blockIdx.x * 4 + wid;
    if (d >= n_dst) return;
    const int h = lane >> 4, ei = lane & 15;
    const float er_h = er[4l * d + h];
    const unsigned beg = offs[d], end = offs[d + 1];
    const int c0 = lane * CPL;
    float m = -INFINITY, s = 0.f, acc0 = 0.f, acc1 = 0.f;

    for (unsigned base = beg; base < end; base += 16) {
        const unsigned na = min(16u, end - base);
        const unsigned sv = ssrc[base + ((unsigned)ei < na ? (unsigned)ei : 0u)];
        float xv = -INFINITY;
        if ((unsigned)ei < na) {
            float x = el[4l * sv + h] + er_h;
            xv = (x >= 0.f) ? x : LRELU_S * x;
        }
        // chunk max within the 16-lane group
        float cm = xv;
#pragma unroll
        for (int off = 1; off < 16; off <<= 1) cm = fmaxf(cm, __shfl_xor(cm, off));
        const float mn = fmaxf(m, cm);
        const float corr = __expf(m - mn);        // first chunk: exp(-inf - finite)=0
        const float p = __expf(xv - mn);          // invalid lanes: exp(-inf)=0
        float ps = p;
#pragma unroll
        for (int off = 1; off < 16; off <<= 1) ps += __shfl_xor(ps, off);
        s = s * corr + ps;
        acc0 *= corr; acc1 *= corr;
        m = mn;
        // serial accumulate: shfl p + bf16 fs row chunk
        unsigned sc = (unsigned)__shfl((int)sv, 0);
        unsigned fc = 0; unsigned short f1c = 0;
        if (CPL == 2) fc  = *reinterpret_cast<const unsigned*>(fsb + (long)sc * CH + c0);
        else          f1c = fsb[(long)sc * CH + c0];
        for (unsigned j = 0; j < na; ++j) {
            const float pj = __shfl(p, (int)((h << 4) | j));
            unsigned f = fc; unsigned short f1 = f1c;
            if (j + 1 < na) {
                unsigned sn = (unsigned)__shfl((int)sv, (int)(j + 1));
                if (CPL == 2) fc  = *reinterpret_cast<const unsigned*>(fsb + (long)sn * CH + c0);
                else          f1c = fsb[(long)sn * CH + c0];
            }
            if (CPL == 2) {
                acc0 += pj * __uint_as_float((f & 0xFFFFu) << 16);
                acc1 += pj * __uint_as_float((f >> 16) << 16);
            } else {
                acc0 += pj * bf2f(f1);
            }
        }
    }
    const float inv = (s > 0.f) ? 1.f / s : 0.f;
    if (CPL == 1) {
        float r = res0[(long)d * 64 + c0];
        out[(long)d * 64 + c0] = fmaxf(acc0 * inv + r + bias[c0], 0.f);
    } else {
        float2 r = (c0 < 64) ? *reinterpret_cast<const float2*>(res0 + (long)d * 64 + c0)
                             : *reinterpret_cast<const float2*>(res1 + (long)d * 64 + (c0 - 64));
        float2 o;
        o.x = fmaxf(acc0 * inv + r.x + bias[c0], 0.f);
        o.y = fmaxf(acc1 * inv + r.y + bias[c0 + 1], 0.f);
        *reinterpret_cast<float2*>(out + (long)d * 128 + c0) = o;
    }
}

// ---------------- comm mailbox mean: bf16 m table ----------------
__global__ __launch_bounds__(256) void comm_gather_k(const unsigned* __restrict__ offs,
                                                     const unsigned* __restrict__ ssrc,
                                                     const unsigned short* __restrict__ mb,
                                                     const float* __restrict__ dinv,
                                                     float* __restrict__ y, int n) {
    const int wid = threadIdx.x >> 6;
    const int lane = threadIdx.x & 63;
    const int d = blockIdx.x * 4 + wid;
    if (d >= n) return;
    const unsigned beg = offs[d], end = offs[d + 1];
    float acc = 0.f;
    for (unsigned base = beg; base < end; base += 64) {
        const unsigned na = min(64u, end - base);
        const unsigned sv = ssrc[base + ((unsigned)lane < na ? (unsigned)lane : 0u)];
        unsigned sc = (unsigned)__shfl((int)sv, 0);
        float fn = bf2f(mb[(long)sc * 64 + lane]);
        for (unsigned j = 0; j < na; ++j) {
            float f = fn;
            if (j + 1 < na) {
                unsigned s2 = (unsigned)__shfl((int)sv, (int)(j + 1));
                fn = bf2f(mb[(long)s2 * 64 + lane]);
            }
            acc += f;
        }
    }
    y[(long)d * 64 + lane] = acc * dinv[d];
}

// ---------------- GRU pointwise (bf16 gi/gh) ----------------
__global__ void gru_k(const unsigned short* __restrict__ gi, const unsigned short* __restrict__ gh,
                      const float* __restrict__ hprev, float* __restrict__ hout, int n) {
    int i = blockIdx.x * blockDim.x + threadIdx.x;
    if (i >= n) return;
    int row = i >> 7, j = i & 127;
    const unsigned short* gir = gi + (long)row * 384;
    const unsigned short* ghr = gh + (long)row * 384;
    float r  = 1.f / (1.f + __expf(-(bf2f(gir[j]) + bf2f(ghr[j]))));
    float zg = 1.f / (1.f + __expf(-(bf2f(gir[j + 128]) + bf2f(ghr[j + 128]))));
    float nn = tanhf(bf2f(gir[j + 256]) + r * bf2f(ghr[j + 256]));
    hout[i] = (1.f - zg) * nn + zg * hprev[i];
}

__global__ void out_k(const float* __restrict__ h, const float* __restrict__ w,
                      const float* __restrict__ b, float* __restrict__ out, int n) {
    int i = blockIdx.x * blockDim.x + threadIdx.x;
    if (i >= n) return;
    float acc[OUTD];
#pragma unroll
    for (int j = 0; j < OUTD; ++j) acc[j] = b[j];
    for (int k = 0; k < 128; ++k) {
        float v = h[(long)i * 128 + k];
#pragma unroll
        for (int j = 0; j < OUTD; ++j) acc[j] += v * w[k * OUTD + j];
    }
#pragma unroll
    for (int j = 0; j < OUTD; ++j) out[(long)i * OUTD + j] = acc[j];
}

__global__ void copy_k(const float* __restrict__ s, float* __restrict__ d, int n) {
    int i = blockIdx.x * blockDim.x + threadIdx.x;
    if (i < n) d[i] = s[i];
}

// ---------------- launcher ----------------
extern "C" void kernel_launch(void* const* d_in, const int* in_sizes, int n_in,
                              void* d_out, int out_size, void* d_ws, size_t ws_size,
                              hipStream_t stream) {
    const float* feat_gt    = (const float*)d_in[0];
    const float* feat_agent = (const float*)d_in[1];
    const float* z_in       = (const float*)d_in[2];
    const int*   gt_src     = (const int*)d_in[3];
    const int*   gt_dst     = (const int*)d_in[4];
    const int*   comm_src   = (const int*)d_in[5];
    const int*   comm_dst   = (const int*)d_in[6];
    const float* w1_src = (const float*)d_in[7];
    const float* w1_dst = (const float*)d_in[8];
    const float* a1_l   = (const float*)d_in[9];
    const float* a1_r   = (const float*)d_in[10];
    const float* b1     = (const float*)d_in[11];
    const float* w2_src = (const float*)d_in[12];
    const float* w2_dst = (const float*)d_in[13];
    const float* a2_l   = (const float*)d_in[14];
    const float* a2_r   = (const float*)d_in[15];
    const float* b2     = (const float*)d_in[16];
    const float* enc_w1 = (const float*)d_in[17];
    const float* enc_b1 = (const float*)d_in[18];
    const float* enc_w2 = (const float*)d_in[19];
    const float* enc_b2 = (const float*)d_in[20];
    const float* gw_ih  = (const float*)d_in[21];
    const float* gw_hh  = (const float*)d_in[22];
    const float* gb_ih  = (const float*)d_in[23];
    const float* gb_hh  = (const float*)d_in[24];
    const float* out_w  = (const float*)d_in[25];
    const float* out_b  = (const float*)d_in[26];

    float* ws = (float*)d_ws;
    unsigned* wsu = (unsigned*)d_ws;
    unsigned short* wb = (unsigned short*)(ws + O_WB);
    float* out = (float*)d_out;

    auto blk = [](long n) { return dim3((unsigned)((n + 255) / 256)); };
    const dim3 T(256);

    // ---------- CSR for gt graph ----------
    fill_u32_k<<<blk(N_AG), T, 0, stream>>>(wsu + O_CNT, 0u, N_AG);
    count_k<<<blk(E_GT), T, 0, stream>>>(gt_dst, wsu + O_CNT, E_GT);
    scan_k<<<1, 1024, 0, stream>>>(wsu + O_CNT, wsu + O_OFFS_GT, wsu + O_CUR, N_AG);
    scatter_k<<<blk(E_GT), T, 0, stream>>>(gt_src, gt_dst, wsu + O_CUR, wsu + O_SRT_GT, E_GT);
    // ---------- CSR for comm graph (+ dinv) ----------
    fill_u32_k<<<blk(N_AG), T, 0, stream>>>(wsu + O_CNT, 0u, N_AG);
    count_k<<<blk(E_COMM), T, 0, stream>>>(comm_dst, wsu + O_CNT, E_COMM);
    recip_cnt_k<<<blk(N_AG), T, 0, stream>>>(wsu + O_CNT, ws + O_DINV, N_AG);
    scan_k<<<1, 1024, 0, stream>>>(wsu + O_CNT, wsu + O_OFFS_CM, wsu + O_CUR, N_AG);
    scatter_k<<<blk(E_COMM), T, 0, stream>>>(comm_src, comm_dst, wsu + O_CUR, wsu + O_SRT_CM, E_COMM);

    // ---------- bf16 weight transposes ----------
    wconv_k<<<blk(64 * 32), T, 0, stream>>>(w1_src, wb + WB_FS, 32, 64);            // rows 0..63
    wconv_k<<<blk(128 * 32), T, 0, stream>>>(w2_src, wb + WB_FS + 64 * 32, 32, 128); // rows 64..191
    wconv_k<<<blk(128 * 128), T, 0, stream>>>(enc_w1, wb + WB_E1, 128, 128);
    wconv_k<<<blk(64 * 128), T, 0, stream>>>(enc_w2, wb + WB_E2, 128, 64);
    wconv_k<<<blk(384 * 192), T, 0, stream>>>(gw_ih, wb + WB_GI, 192, 384);
    wconv_k<<<blk(384 * 128), T, 0, stream>>>(gw_hh, wb + WB_GH, 128, 384);

    // ---------- attention vectors + el/er ----------
    float* VL1 = ws + O_V, *VR1 = ws + O_V + 128, *VL2 = ws + O_V + 384, *VR2 = ws + O_V + 512;
    make_v_k<<<1, 256, 0, stream>>>(w1_src, a1_l, VL1, 32, 16);
    make_v_k<<<1, 256, 0, stream>>>(w1_dst, a1_r, VR1, 64, 16);
    make_v_k<<<1, 256, 0, stream>>>(w2_src, a2_l, VL2, 32, 32);
    make_v_k<<<dim3(2), 256, 0, stream>>>(w2_dst, a2_r, VR2, 128, 32);
    rowvec8_k<<<blk(N_GT), T, 0, stream>>>(feat_gt, VL1, VL2, ws + O_EL1, ws + O_EL2, N_GT);
    rowvec_k<<<blk(N_AG), T, 0, stream>>>(feat_agent, VR1, ws + O_ER1, N_AG, 64);

    const int MB_GT = (N_GT + 63) / 64, MB_AG = (N_AG + 63) / 64;
    unsigned short* fsb1 = (unsigned short*)(ws + O_FSB1);
    unsigned short* fsb2 = (unsigned short*)(ws + O_FSB2);

    // ---------- fused fs1+fs2 producer ----------
    fs_gemm_k<<<dim3(3, MB_GT), T, 0, stream>>>(feat_gt, wb + WB_FS, fsb1, fsb2, N_GT);

    // ---------- GAT1 ----------
    gat_fused_k<64><<<dim3((N_AG + 3) / 4), T, 0, stream>>>(wsu + O_OFFS_GT, wsu + O_SRT_GT,
        ws + O_EL1, ws + O_ER1, fsb1, feat_agent, nullptr, b1, ws + O_RST1, N_AG);

    // ---------- GAT2 ----------
    rowvec2_k<<<blk(N_AG), T, 0, stream>>>(ws + O_RST1, feat_agent, VR2, ws + O_ER2, N_AG, 64, 64);
    gat_fused_k<128><<<dim3((N_AG + 3) / 4), T, 0, stream>>>(wsu + O_OFFS_GT, wsu + O_SRT_GT,
        ws + O_EL2, ws + O_ER2, fsb2, ws + O_RST1, feat_agent, b2, ws + O_RST2, N_AG);

    // ---------- comm steps ----------
    float* h = ws + O_RST2;
    unsigned short* mb = (unsigned short*)(ws + O_M);
    unsigned short* gib = (unsigned short*)(ws + O_GI);
    unsigned short* ghb = (unsigned short*)(ws + O_GH);
    for (int step = 0; step < 2; ++step) {
        const float* zz = (step == 0) ? z_in : h;
        mgemm_k<1, 0><<<dim3(2, MB_AG), T, 0, stream>>>(h, nullptr, 128, wb + WB_E1, enc_b1, ws + O_T1, N_AG, 128, 128);
        mgemm_k<1, 1><<<dim3(1, MB_AG), T, 0, stream>>>(ws + O_T1, nullptr, 128, wb + WB_E2, enc_b2, mb, N_AG, 64, 128);
        comm_gather_k<<<dim3((N_AG + 3) / 4), T, 0, stream>>>(wsu + O_OFFS_CM, wsu + O_SRT_CM,
            mb, ws + O_DINV, ws + O_Y, N_AG);
        mgemm_k<0, 1><<<dim3(6, MB_AG), T, 0, stream>>>(h, ws + O_Y, 128, wb + WB_GI, gb_ih, gib, N_AG, 384, 192);
        mgemm_k<0, 1><<<dim3(6, MB_AG), T, 0, stream>>>(zz, nullptr, 128, wb + WB_GH, gb_hh, ghb, N_AG, 384, 128);
        gru_k<<<blk((long)N_AG * 128), T, 0, stream>>>(gib, ghb, zz, h, N_AG * 128);
    }

    // ---------- outputs ----------
    out_k<<<blk(N_AG), T, 0, stream>>>(h, out_w, out_b, out, N_AG);
    copy_k<<<blk((long)N_AG * 128), T, 0, stream>>>(h, out + (long)N_AG * OUTD, N_AG * 128);
}

// Round 6
// 605.484 us; speedup vs baseline: 3.0454x; 1.1046x over previous
//
#include <hip/hip_runtime.h>
#include <math.h>

// ---------------- problem constants ----------------
#define NHEAD 4
#define LRELU_S 0.2f
constexpr int N_GT = 100000, N_AG = 20000;
constexpr int E_GT = 640000, E_COMM = 320000;
constexpr int OUTD = 5;

// ---------------- workspace layout (float/u32 units of 4B) ----------------
constexpr long O_FSB1    = 0;          // N_GT*64 bf16 = 3.2M units
constexpr long O_FSB2    = 3200000;    // N_GT*128 bf16 = 6.4M units -> 9.6M
constexpr long O_EL1     = 12800000;   // 100000*4
constexpr long O_EL2     = 13200000;   // 100000*4
constexpr long O_RST1    = 13600000;   // 20000*64  (h_vis1)
constexpr long O_ER1     = 14880000;   // 20000*4
constexpr long O_ER2     = 14960000;   // 20000*4 -> 15.04M
constexpr long O_RST2    = 17600000;   // 20000*128 (h, persists)
constexpr long O_DINV    = 20160000;   // 20000
constexpr long O_OFFS_GT = 20180000;   // 20001 u32
constexpr long O_SRT_GT  = 20200004;   // 640000 u32
constexpr long O_OFFS_CM = 20840004;   // 20001 u32
constexpr long O_SRT_CM  = 20860008;   // 320000 u32
constexpr long O_CNT     = 21180008;   // 20000 u32
constexpr long O_CUR     = 21200008;   // 20000 u32
constexpr long O_V       = 21220008;   // VL1(128) VR1(256) VL2(128) VR2(512)
constexpr long O_WB      = 21300000;   // bf16 weights (shorts)
// phase C aliases (fsb1/fsb2/EL dead by then)
constexpr long O_GH = 0;               // 20000*384 bf16 = 3.84M units
constexpr long O_T1 = 7680000;         // 20000*128 fp32 -> 10.24M
constexpr long O_M  = 10240000;        // 20000*64 bf16 = 0.32M units
constexpr long O_GI = 7680000;         // 20000*384 bf16 -> 11.52M (overlays dead T1; M consumed before GI write)
constexpr long O_Y  = 15360000;        // 20000*64 fp32 -> 16.64M

// bf16 weight sub-offsets (shorts, relative to O_WB)
constexpr long WB_FS = 0;        // combined [w1|w2] transposed: 192x32
constexpr long WB_E1 = 6144;     // 128x128
constexpr long WB_E2 = 22528;    // 64x128
constexpr long WB_GI = 30720;    // 384x192
constexpr long WB_GH = 104448;   // 384x128 -> end 153600

using bf8      = __attribute__((ext_vector_type(8))) short;
using f32x4v   = __attribute__((ext_vector_type(4))) float;
using ushort8v = __attribute__((ext_vector_type(8))) unsigned short;

__device__ __forceinline__ unsigned short f2bf(float x) {
    unsigned u = __float_as_uint(x);
    u += 0x7FFFu + ((u >> 16) & 1u);
    return (unsigned short)(u >> 16);
}
__device__ __forceinline__ float bf2f(unsigned short u) {
    return __uint_as_float(((unsigned)u) << 16);
}

__global__ void fill_u32_k(unsigned* __restrict__ p, unsigned v, int n) {
    int i = blockIdx.x * blockDim.x + threadIdx.x;
    if (i < n) p[i] = v;
}

// ---------------- CSR build ----------------
__global__ void count_k(const int* __restrict__ dst, unsigned* __restrict__ cnt, int E) {
    int e = blockIdx.x * blockDim.x + threadIdx.x;
    if (e < E) atomicAdd(cnt + dst[e], 1u);
}

__global__ __launch_bounds__(1024) void scan_k(const unsigned* __restrict__ cnt,
                                               unsigned* __restrict__ offs,
                                               unsigned* __restrict__ cursor, int n) {
    __shared__ unsigned part[1024];
    int t = threadIdx.x;
    int chunk = (n + 1023) / 1024;
    int b = t * chunk, e = min(n, b + chunk);
    unsigned s = 0;
    for (int i = b; i < e; ++i) s += cnt[i];
    part[t] = s;
    __syncthreads();
    for (int off = 1; off < 1024; off <<= 1) {
        unsigned v = (t >= off) ? part[t - off] : 0u;
        __syncthreads();
        part[t] += v;
        __syncthreads();
    }
    unsigned run = (t > 0) ? part[t - 1] : 0u;
    for (int i = b; i < e; ++i) {
        offs[i] = run; cursor[i] = run;
        run += cnt[i];
    }
    if (t == 1023) offs[n] = run;
}

__global__ void scatter_k(const int* __restrict__ src, const int* __restrict__ dst,
                          unsigned* __restrict__ cursor, unsigned* __restrict__ sorted, int E) {
    int e = blockIdx.x * blockDim.x + threadIdx.x;
    if (e < E) {
        unsigned p = atomicAdd(cursor + dst[e], 1u);
        sorted[p] = (unsigned)src[e];
    }
}

__global__ void recip_cnt_k(const unsigned* __restrict__ cnt, float* __restrict__ dinv, int n) {
    int i = blockIdx.x * blockDim.x + threadIdx.x;
    if (i < n) dinv[i] = 1.0f / fmaxf((float)cnt[i], 1.0f);
}

// ---------------- attention projection vectors ----------------
__global__ void make_v_k(const float* __restrict__ w, const float* __restrict__ a,
                         float* __restrict__ v, int K, int dh) {
    int i = blockIdx.x * blockDim.x + threadIdx.x;
    if (i >= K * 4) return;
    int k = i >> 2, h = i & 3;
    float s = 0.f;
    for (int j = 0; j < dh; ++j) s += w[k * (4 * dh) + h * dh + j] * a[h * dh + j];
    v[k * 4 + h] = s;
}

__global__ void rowvec8_k(const float* __restrict__ f, const float* __restrict__ v1,
                          const float* __restrict__ v2, float* __restrict__ o1,
                          float* __restrict__ o2, int n) {
    int i = blockIdx.x * blockDim.x + threadIdx.x;
    if (i >= n) return;
    float a[8] = {};
    const float* fp = f + (long)i * 32;
    for (int k = 0; k < 32; ++k) {
        float x = fp[k];
#pragma unroll
        for (int j = 0; j < 4; ++j) a[j] += x * v1[4 * k + j];
#pragma unroll
        for (int j = 0; j < 4; ++j) a[4 + j] += x * v2[4 * k + j];
    }
    *reinterpret_cast<float4*>(o1 + 4l * i) = {a[0], a[1], a[2], a[3]};
    *reinterpret_cast<float4*>(o2 + 4l * i) = {a[4], a[5], a[6], a[7]};
}

__global__ void rowvec_k(const float* __restrict__ f, const float* __restrict__ v,
                         float* __restrict__ out, int n, int K) {
    int i = blockIdx.x * blockDim.x + threadIdx.x;
    if (i >= n) return;
    float a0 = 0, a1 = 0, a2 = 0, a3 = 0;
    const float* fp = f + (long)i * K;
    for (int k = 0; k < K; ++k) {
        float x = fp[k];
        a0 += x * v[4 * k]; a1 += x * v[4 * k + 1];
        a2 += x * v[4 * k + 2]; a3 += x * v[4 * k + 3];
    }
    float4 r = {a0, a1, a2, a3};
    *reinterpret_cast<float4*>(out + 4l * i) = r;
}

__global__ void rowvec2_k(const float* __restrict__ f1, const float* __restrict__ f2,
                          const float* __restrict__ v, float* __restrict__ out, int n, int K1, int K2) {
    int i = blockIdx.x * blockDim.x + threadIdx.x;
    if (i >= n) return;
    float a0 = 0, a1 = 0, a2 = 0, a3 = 0;
    const float* fp = f1 + (long)i * K1;
    for (int k = 0; k < K1; ++k) {
        float x = fp[k];
        a0 += x * v[4 * k]; a1 += x * v[4 * k + 1];
        a2 += x * v[4 * k + 2]; a3 += x * v[4 * k + 3];
    }
    const float* gp = f2 + (long)i * K2;
    const float* v2 = v + 4l * K1;
    for (int k = 0; k < K2; ++k) {
        float x = gp[k];
        a0 += x * v2[4 * k]; a1 += x * v2[4 * k + 1];
        a2 += x * v2[4 * k + 2]; a3 += x * v2[4 * k + 3];
    }
    float4 r = {a0, a1, a2, a3};
    *reinterpret_cast<float4*>(out + 4l * i) = r;
}

// ---------------- weight convert+transpose ----------------
__global__ void wconv_k(const float* __restrict__ W, unsigned short* __restrict__ Bt, int K, int N) {
    int i = blockIdx.x * blockDim.x + threadIdx.x;
    if (i >= K * N) return;
    int n = i / K, k = i - n * K;
    Bt[i] = f2bf(W[(long)k * N + n]);
}

// ---------------- bf16 MFMA GEMM ----------------
template <int ACT, int OB>
__global__ __launch_bounds__(256) void mgemm_k(const float* __restrict__ A,
                                               const float* __restrict__ A2, int K1,
                                               const unsigned short* __restrict__ Bt,
                                               const float* __restrict__ bias,
                                               void* __restrict__ Cv,
                                               int M, int N, int K) {
    __shared__ unsigned short As[64][40];
    __shared__ unsigned short Bs[64][40];
    const int tid = threadIdx.x;
    const int lane = tid & 63, wv = tid >> 6;
    const int wm = wv & 1, wn = wv >> 1;
    const int quad = lane >> 4, l16 = lane & 15;
    const int m0 = blockIdx.y * 64, n0 = blockIdx.x * 64;
    const int K2 = K - K1;
    f32x4v acc[2][2] = {};
    const int rA = tid >> 3, cA = (tid & 7) * 4;
    const int rB = tid >> 2, cB = (tid & 3) * 8;

    for (int k0 = 0; k0 < K; k0 += 32) {
#pragma unroll
        for (int half = 0; half < 2; ++half) {
            const int r = rA + half * 32;
            const int row = m0 + r;
            const int kg = k0 + cA;
            float4 v = {0.f, 0.f, 0.f, 0.f};
            if (row < M) {
                v = (kg < K1) ? *reinterpret_cast<const float4*>(A + (long)row * K1 + kg)
                              : *reinterpret_cast<const float4*>(A2 + (long)row * K2 + (kg - K1));
            }
            ushort4 b;
            b.x = f2bf(v.x); b.y = f2bf(v.y); b.z = f2bf(v.z); b.w = f2bf(v.w);
            *reinterpret_cast<ushort4*>(&As[r][cA]) = b;
        }
        *reinterpret_cast<ushort8v*>(&Bs[rB][cB]) =
            *reinterpret_cast<const ushort8v*>(Bt + (long)(n0 + rB) * K + k0 + cB);
        __syncthreads();

        const bf8 a0 = *reinterpret_cast<const bf8*>(&As[wm * 32 + l16][quad * 8]);
        const bf8 a1 = *reinterpret_cast<const bf8*>(&As[wm * 32 + 16 + l16][quad * 8]);
        const bf8 b0 = *reinterpret_cast<const bf8*>(&Bs[wn * 32 + l16][quad * 8]);
        const bf8 b1 = *reinterpret_cast<const bf8*>(&Bs[wn * 32 + 16 + l16][quad * 8]);
        acc[0][0] = __builtin_amdgcn_mfma_f32_16x16x32_bf16(a0, b0, acc[0][0], 0, 0, 0);
        acc[0][1] = __builtin_amdgcn_mfma_f32_16x16x32_bf16(a0, b1, acc[0][1], 0, 0, 0);
        acc[1][0] = __builtin_amdgcn_mfma_f32_16x16x32_bf16(a1, b0, acc[1][0], 0, 0, 0);
        acc[1][1] = __builtin_amdgcn_mfma_f32_16x16x32_bf16(a1, b1, acc[1][1], 0, 0, 0);
        __syncthreads();
    }

#pragma unroll
    for (int mt = 0; mt < 2; ++mt)
#pragma unroll
        for (int nt = 0; nt < 2; ++nt)
#pragma unroll
            for (int r = 0; r < 4; ++r) {
                const int row = m0 + wm * 32 + mt * 16 + quad * 4 + r;
                const int col = n0 + wn * 32 + nt * 16 + l16;
                if (row < M) {
                    float v = acc[mt][nt][r];
                    if (bias) v += bias[col];
                    if (ACT) v = fmaxf(v, 0.f);
                    if (OB) ((unsigned short*)Cv)[(long)row * N + col] = f2bf(v);
                    else    ((float*)Cv)[(long)row * N + col] = v;
                }
            }
}

// ---------------- fused fs1+fs2 producer ----------------
__global__ __launch_bounds__(256) void fs_gemm_k(const float* __restrict__ A,
                                                 const unsigned short* __restrict__ Btc,
                                                 unsigned short* __restrict__ fsb1,
                                                 unsigned short* __restrict__ fsb2, int M) {
    __shared__ unsigned short As[64][40];
    __shared__ unsigned short Bs[64][40];
    const int tid = threadIdx.x;
    const int lane = tid & 63, wv = tid >> 6;
    const int wm = wv & 1, wn = wv >> 1;
    const int quad = lane >> 4, l16 = lane & 15;
    const int m0 = blockIdx.y * 64, n0 = blockIdx.x * 64;
    f32x4v acc[2][2] = {};
    const int rA = tid >> 3, cA = (tid & 7) * 4;
    const int rB = tid >> 2, cB = (tid & 3) * 8;

#pragma unroll
    for (int half = 0; half < 2; ++half) {
        const int r = rA + half * 32;
        const int row = m0 + r;
        float4 v = {0.f, 0.f, 0.f, 0.f};
        if (row < M) v = *reinterpret_cast<const float4*>(A + (long)row * 32 + cA);
        ushort4 b;
        b.x = f2bf(v.x); b.y = f2bf(v.y); b.z = f2bf(v.z); b.w = f2bf(v.w);
        *reinterpret_cast<ushort4*>(&As[r][cA]) = b;
    }
    *reinterpret_cast<ushort8v*>(&Bs[rB][cB]) =
        *reinterpret_cast<const ushort8v*>(Btc + (long)(n0 + rB) * 32 + cB);
    __syncthreads();

    const bf8 a0 = *reinterpret_cast<const bf8*>(&As[wm * 32 + l16][quad * 8]);
    const bf8 a1 = *reinterpret_cast<const bf8*>(&As[wm * 32 + 16 + l16][quad * 8]);
    const bf8 b0 = *reinterpret_cast<const bf8*>(&Bs[wn * 32 + l16][quad * 8]);
    const bf8 b1 = *reinterpret_cast<const bf8*>(&Bs[wn * 32 + 16 + l16][quad * 8]);
    acc[0][0] = __builtin_amdgcn_mfma_f32_16x16x32_bf16(a0, b0, acc[0][0], 0, 0, 0);
    acc[0][1] = __builtin_amdgcn_mfma_f32_16x16x32_bf16(a0, b1, acc[0][1], 0, 0, 0);
    acc[1][0] = __builtin_amdgcn_mfma_f32_16x16x32_bf16(a1, b0, acc[1][0], 0, 0, 0);
    acc[1][1] = __builtin_amdgcn_mfma_f32_16x16x32_bf16(a1, b1, acc[1][1], 0, 0, 0);

#pragma unroll
    for (int mt = 0; mt < 2; ++mt)
#pragma unroll
        for (int nt = 0; nt < 2; ++nt)
#pragma unroll
            for (int r = 0; r < 4; ++r) {
                const int row = m0 + wm * 32 + mt * 16 + quad * 4 + r;
                const int col = n0 + wn * 32 + nt * 16 + l16;
                if (row < M) {
                    unsigned short v16 = f2bf(acc[mt][nt][r]);
                    if (col < 64) fsb1[(long)row * 64 + col] = v16;
                    else          fsb2[(long)row * 128 + (col - 64)] = v16;
                }
            }
}

// ---------------- fused flash GAT v3b: chunked softmax + 16-deep batched gathers (clamped) ----------------
template <int CH>
__global__ __launch_bounds__(256) void gat_fused_k(
    const unsigned* __restrict__ offs, const unsigned* __restrict__ ssrc,
    const float* __restrict__ el, const float* __restrict__ er,
    const unsigned short* __restrict__ fsb,
    const float* __restrict__ res0, const float* __restrict__ res1,
    const float* __restrict__ bias, float* __restrict__ out, int n_dst, unsigned nsrc)
{
    constexpr int CPL = CH / 64;
    const int wid = threadIdx.x >> 6;
    const int lane = threadIdx.x & 63;
    const int d = blockIdx.x * 4 + wid;
    if (d >= n_dst) return;
    const int h = lane >> 4, ei = lane & 15;
    const float er_h = er[4l * d + h];
    const unsigned beg = offs[d], end = offs[d + 1];
    const int c0 = lane * CPL;
    const unsigned smax = nsrc - 1u;
    float m = -INFINITY, s = 0.f, acc0 = 0.f, acc1 = 0.f;

    for (unsigned base = beg; base < end; base += 16) {
        const unsigned na = min(16u, end - base);
        unsigned sv = ssrc[base + ((unsigned)ei < na ? (unsigned)ei : 0u)];
        sv = min(sv, smax);   // safety clamp: any OOB index becomes a benign wrong-row read
        // batch-issue all 16 row gathers (16 outstanding loads — hide L2/L3 latency)
        unsigned fw[16];
#pragma unroll
        for (int j = 0; j < 16; ++j) {
            const unsigned sj = (unsigned)__shfl((int)sv, j);
            if (CPL == 2) fw[j] = *reinterpret_cast<const unsigned*>(fsb + (long)sj * CH + c0);
            else          fw[j] = fsb[(long)sj * CH + c0];
        }
        float xv = -INFINITY;
        if ((unsigned)ei < na) {
            float x = el[4l * sv + h] + er_h;
            xv = (x >= 0.f) ? x : LRELU_S * x;
        }
        float cm = xv;
#pragma unroll
        for (int off = 1; off < 16; off <<= 1) cm = fmaxf(cm, __shfl_xor(cm, off));
        const float mn = fmaxf(m, cm);
        const float corr = __expf(m - mn);
        const float p = __expf(xv - mn);          // invalid lanes: exp(-inf)=0
        float ps = p;
#pragma unroll
        for (int off = 1; off < 16; off <<= 1) ps += __shfl_xor(ps, off);
        s = s * corr + ps;
        acc0 *= corr; acc1 *= corr;
        m = mn;
#pragma unroll
        for (int j = 0; j < 16; ++j) {
            const float pj = __shfl(p, (h << 4) | j);   // 0 for j >= na
            if (CPL == 2) {
                acc0 += pj * __uint_as_float((fw[j] & 0xFFFFu) << 16);
                acc1 += pj * __uint_as_float((fw[j] >> 16) << 16);
            } else {
                acc0 += pj * bf2f((unsigned short)fw[j]);
            }
        }
    }
    const float inv = (s > 0.f) ? 1.f / s : 0.f;
    if (CPL == 1) {
        float r = res0[(long)d * 64 + c0];
        out[(long)d * 64 + c0] = fmaxf(acc0 * inv + r + bias[c0], 0.f);
    } else {
        float2 r = (c0 < 64) ? *reinterpret_cast<const float2*>(res0 + (long)d * 64 + c0)
                             : *reinterpret_cast<const float2*>(res1 + (long)d * 64 + (c0 - 64));
        float2 o;
        o.x = fmaxf(acc0 * inv + r.x + bias[c0], 0.f);
        o.y = fmaxf(acc1 * inv + r.y + bias[c0 + 1], 0.f);
        *reinterpret_cast<float2*>(out + (long)d * 128 + c0) = o;
    }
}

// ---------------- comm mailbox mean v2b: 16-deep batched gathers (clamped) ----------------
__global__ __launch_bounds__(256) void comm_gather_k(const unsigned* __restrict__ offs,
                                                     const unsigned* __restrict__ ssrc,
                                                     const unsigned short* __restrict__ mb,
                                                     const float* __restrict__ dinv,
                                                     float* __restrict__ y, int n) {
    const int wid = threadIdx.x >> 6;
    const int lane = threadIdx.x & 63;
    const int d = blockIdx.x * 4 + wid;
    if (d >= n) return;
    const unsigned beg = offs[d], end = offs[d + 1];
    const int ei = lane & 15;
    const unsigned smax = (unsigned)n - 1u;
    float acc = 0.f;
    for (unsigned base = beg; base < end; base += 16) {
        const unsigned na = min(16u, end - base);
        unsigned sv = ssrc[base + ((unsigned)ei < na ? (unsigned)ei : 0u)];
        sv = min(sv, smax);
        unsigned short fw[16];
#pragma unroll
        for (int j = 0; j < 16; ++j) {
            const unsigned sj = (unsigned)__shfl((int)sv, j);
            fw[j] = mb[(long)sj * 64 + lane];
        }
#pragma unroll
        for (int j = 0; j < 16; ++j)
            if ((unsigned)j < na) acc += bf2f(fw[j]);
    }
    y[(long)d * 64 + lane] = acc * dinv[d];
}

// ---------------- GRU pointwise (bf16 gi/gh) ----------------
__global__ void gru_k(const unsigned short* __restrict__ gi, const unsigned short* __restrict__ gh,
                      const float* __restrict__ hprev, float* __restrict__ hout, int n) {
    int i = blockIdx.x * blockDim.x + threadIdx.x;
    if (i >= n) return;
    int row = i >> 7, j = i & 127;
    const unsigned short* gir = gi + (long)row * 384;
    const unsigned short* ghr = gh + (long)row * 384;
    float r  = 1.f / (1.f + __expf(-(bf2f(gir[j]) + bf2f(ghr[j]))));
    float zg = 1.f / (1.f + __expf(-(bf2f(gir[j + 128]) + bf2f(ghr[j + 128]))));
    float nn = tanhf(bf2f(gir[j + 256]) + r * bf2f(ghr[j + 256]));
    hout[i] = (1.f - zg) * nn + zg * hprev[i];
}

__global__ void out_k(const float* __restrict__ h, const float* __restrict__ w,
                      const float* __restrict__ b, float* __restrict__ out, int n) {
    int i = blockIdx.x * blockDim.x + threadIdx.x;
    if (i >= n) return;
    float acc[OUTD];
#pragma unroll
    for (int j = 0; j < OUTD; ++j) acc[j] = b[j];
    for (int k = 0; k < 128; ++k) {
        float v = h[(long)i * 128 + k];
#pragma unroll
        for (int j = 0; j < OUTD; ++j) acc[j] += v * w[k * OUTD + j];
    }
#pragma unroll
    for (int j = 0; j < OUTD; ++j) out[(long)i * OUTD + j] = acc[j];
}

__global__ void copy_k(const float* __restrict__ s, float* __restrict__ d, int n) {
    int i = blockIdx.x * blockDim.x + threadIdx.x;
    if (i < n) d[i] = s[i];
}

// ---------------- launcher ----------------
extern "C" void kernel_launch(void* const* d_in, const int* in_sizes, int n_in,
                              void* d_out, int out_size, void* d_ws, size_t ws_size,
                              hipStream_t stream) {
    const float* feat_gt    = (const float*)d_in[0];
    const float* feat_agent = (const float*)d_in[1];
    const float* z_in       = (const float*)d_in[2];
    const int*   gt_src     = (const int*)d_in[3];
    const int*   gt_dst     = (const int*)d_in[4];
    const int*   comm_src   = (const int*)d_in[5];
    const int*   comm_dst   = (const int*)d_in[6];
    const float* w1_src = (const float*)d_in[7];
    const float* w1_dst = (const float*)d_in[8];
    const float* a1_l   = (const float*)d_in[9];
    const float* a1_r   = (const float*)d_in[10];
    const float* b1     = (const float*)d_in[11];
    const float* w2_src = (const float*)d_in[12];
    const float* w2_dst = (const float*)d_in[13];
    const float* a2_l   = (const float*)d_in[14];
    const float* a2_r   = (const float*)d_in[15];
    const float* b2     = (const float*)d_in[16];
    const float* enc_w1 = (const float*)d_in[17];
    const float* enc_b1 = (const float*)d_in[18];
    const float* enc_w2 = (const float*)d_in[19];
    const float* enc_b2 = (const float*)d_in[20];
    const float* gw_ih  = (const float*)d_in[21];
    const float* gw_hh  = (const float*)d_in[22];
    const float* gb_ih  = (const float*)d_in[23];
    const float* gb_hh  = (const float*)d_in[24];
    const float* out_w  = (const float*)d_in[25];
    const float* out_b  = (const float*)d_in[26];

    float* ws = (float*)d_ws;
    unsigned* wsu = (unsigned*)d_ws;
    unsigned short* wb = (unsigned short*)(ws + O_WB);
    float* out = (float*)d_out;

    auto blk = [](long n) { return dim3((unsigned)((n + 255) / 256)); };
    const dim3 T(256);

    // ---------- CSR for gt graph ----------
    fill_u32_k<<<blk(N_AG), T, 0, stream>>>(wsu + O_CNT, 0u, N_AG);
    count_k<<<blk(E_GT), T, 0, stream>>>(gt_dst, wsu + O_CNT, E_GT);
    scan_k<<<1, 1024, 0, stream>>>(wsu + O_CNT, wsu + O_OFFS_GT, wsu + O_CUR, N_AG);
    scatter_k<<<blk(E_GT), T, 0, stream>>>(gt_src, gt_dst, wsu + O_CUR, wsu + O_SRT_GT, E_GT);
    // ---------- CSR for comm graph (+ dinv) ----------
    fill_u32_k<<<blk(N_AG), T, 0, stream>>>(wsu + O_CNT, 0u, N_AG);
    count_k<<<blk(E_COMM), T, 0, stream>>>(comm_dst, wsu + O_CNT, E_COMM);
    recip_cnt_k<<<blk(N_AG), T, 0, stream>>>(wsu + O_CNT, ws + O_DINV, N_AG);
    scan_k<<<1, 1024, 0, stream>>>(wsu + O_CNT, wsu + O_OFFS_CM, wsu + O_CUR, N_AG);
    scatter_k<<<blk(E_COMM), T, 0, stream>>>(comm_src, comm_dst, wsu + O_CUR, wsu + O_SRT_CM, E_COMM);

    // ---------- bf16 weight transposes ----------
    wconv_k<<<blk(64 * 32), T, 0, stream>>>(w1_src, wb + WB_FS, 32, 64);
    wconv_k<<<blk(128 * 32), T, 0, stream>>>(w2_src, wb + WB_FS + 64 * 32, 32, 128);
    wconv_k<<<blk(128 * 128), T, 0, stream>>>(enc_w1, wb + WB_E1, 128, 128);
    wconv_k<<<blk(64 * 128), T, 0, stream>>>(enc_w2, wb + WB_E2, 128, 64);
    wconv_k<<<blk(384 * 192), T, 0, stream>>>(gw_ih, wb + WB_GI, 192, 384);
    wconv_k<<<blk(384 * 128), T, 0, stream>>>(gw_hh, wb + WB_GH, 128, 384);

    // ---------- attention vectors + el/er ----------
    float* VL1 = ws + O_V, *VR1 = ws + O_V + 128, *VL2 = ws + O_V + 384, *VR2 = ws + O_V + 512;
    make_v_k<<<1, 256, 0, stream>>>(w1_src, a1_l, VL1, 32, 16);
    make_v_k<<<1, 256, 0, stream>>>(w1_dst, a1_r, VR1, 64, 16);
    make_v_k<<<1, 256, 0, stream>>>(w2_src, a2_l, VL2, 32, 32);
    make_v_k<<<dim3(2), 256, 0, stream>>>(w2_dst, a2_r, VR2, 128, 32);
    rowvec8_k<<<blk(N_GT), T, 0, stream>>>(feat_gt, VL1, VL2, ws + O_EL1, ws + O_EL2, N_GT);
    rowvec_k<<<blk(N_AG), T, 0, stream>>>(feat_agent, VR1, ws + O_ER1, N_AG, 64);

    const int MB_GT = (N_GT + 63) / 64, MB_AG = (N_AG + 63) / 64;
    unsigned short* fsb1 = (unsigned short*)(ws + O_FSB1);
    unsigned short* fsb2 = (unsigned short*)(ws + O_FSB2);

    // ---------- fused fs1+fs2 producer ----------
    fs_gemm_k<<<dim3(3, MB_GT), T, 0, stream>>>(feat_gt, wb + WB_FS, fsb1, fsb2, N_GT);

    // ---------- GAT1 ----------
    gat_fused_k<64><<<dim3((N_AG + 3) / 4), T, 0, stream>>>(wsu + O_OFFS_GT, wsu + O_SRT_GT,
        ws + O_EL1, ws + O_ER1, fsb1, feat_agent, nullptr, b1, ws + O_RST1, N_AG, N_GT);

    // ---------- GAT2 ----------
    rowvec2_k<<<blk(N_AG), T, 0, stream>>>(ws + O_RST1, feat_agent, VR2, ws + O_ER2, N_AG, 64, 64);
    gat_fused_k<128><<<dim3((N_AG + 3) / 4), T, 0, stream>>>(wsu + O_OFFS_GT, wsu + O_SRT_GT,
        ws + O_EL2, ws + O_ER2, fsb2, ws + O_RST1, feat_agent, b2, ws + O_RST2, N_AG, N_GT);

    // ---------- comm steps ----------
    float* h = ws + O_RST2;
    unsigned short* mb = (unsigned short*)(ws + O_M);
    unsigned short* gib = (unsigned short*)(ws + O_GI);
    unsigned short* ghb = (unsigned short*)(ws + O_GH);
    for (int step = 0; step < 2; ++step) {
        const float* zz = (step == 0) ? z_in : h;
        mgemm_k<1, 0><<<dim3(2, MB_AG), T, 0, stream>>>(h, nullptr, 128, wb + WB_E1, enc_b1, ws + O_T1, N_AG, 128, 128);
        mgemm_k<1, 1><<<dim3(1, MB_AG), T, 0, stream>>>(ws + O_T1, nullptr, 128, wb + WB_E2, enc_b2, mb, N_AG, 64, 128);
        comm_gather_k<<<dim3((N_AG + 3) / 4), T, 0, stream>>>(wsu + O_OFFS_CM, wsu + O_SRT_CM,
            mb, ws + O_DINV, ws + O_Y, N_AG);
        mgemm_k<0, 1><<<dim3(6, MB_AG), T, 0, stream>>>(h, ws + O_Y, 128, wb + WB_GI, gb_ih, gib, N_AG, 384, 192);
        mgemm_k<0, 1><<<dim3(6, MB_AG), T, 0, stream>>>(zz, nullptr, 128, wb + WB_GH, gb_hh, ghb, N_AG, 384, 128);
        gru_k<<<blk((long)N_AG * 128), T, 0, stream>>>(gib, ghb, zz, h, N_AG * 128);
    }

    // ---------- outputs ----------
    out_k<<<blk(N_AG), T, 0, stream>>>(h, out_w, out_b, out, N_AG);
    copy_k<<<blk((long)N_AG * 128), T, 0, stream>>>(h, out + (long)N_AG * OUTD, N_AG * 128);
}

// Round 7
// 493.499 us; speedup vs baseline: 3.7365x; 1.2269x over previous
//
#include <hip/hip_runtime.h>
#include <math.h>

// ---------------- problem constants ----------------
#define NHEAD 4
#define LRELU_S 0.2f
constexpr int N_GT = 100000, N_AG = 20000;
constexpr int E_GT = 640000, E_COMM = 320000;
constexpr int OUTD = 5;

// ---------------- workspace layout (float/u32 units of 4B) ----------------
constexpr long O_FSB1    = 0;          // N_GT*64 bf16 = 3.2M units
constexpr long O_FSB2    = 3200000;    // N_GT*128 bf16 = 6.4M units -> 9.6M
constexpr long O_EL1     = 12800000;   // 100000*4
constexpr long O_EL2     = 13200000;   // 100000*4
constexpr long O_RST1    = 13600000;   // 20000*64  (h_vis1)
constexpr long O_ER1     = 14880000;   // 20000*4
constexpr long O_ER2     = 14960000;   // 20000*4 -> 15.04M
constexpr long O_RST2    = 17600000;   // 20000*128 (h, persists)
constexpr long O_DINV    = 20160000;   // 20000
constexpr long O_OFFS_GT = 20180000;   // 20001 u32
constexpr long O_SRT_GT  = 20200004;   // 640000 u32
constexpr long O_OFFS_CM = 20840004;   // 20001 u32
constexpr long O_SRT_CM  = 20860008;   // 320000 u32
constexpr long O_CNT_GT  = 21180008;   // 20000 u32
constexpr long O_CNT_CM  = 21200008;   // 20000 u32 (contiguous with CNT_GT: one fill)
constexpr long O_V       = 21220008;   // 1024 floats: VL1(128) VR1(256) VL2(128) VR2(512)
constexpr long O_WB      = 21300000;   // bf16 weights, 153600 shorts = 76800 floats -> 21376800
constexpr long O_RANK_GT = 21500000;   // 640000 u32 -> 22140000
constexpr long O_RANK_CM = 22140000;   // 320000 u32 -> 22460000
// phase C aliases (fsb1/fsb2/EL dead by then)
constexpr long O_GH = 0;               // 20000*384 bf16 = 3.84M units
constexpr long O_T1 = 7680000;         // 20000*128 fp32 -> 10.24M
constexpr long O_M  = 10240000;        // 20000*64 bf16 = 0.32M units
constexpr long O_GI = 7680000;         // 20000*384 bf16 -> 11.52M (overlays dead T1; M consumed before GI write)
constexpr long O_Y  = 15360000;        // 20000*64 fp32 -> 16.64M

// bf16 weight sub-offsets (shorts, relative to O_WB) — contiguous ladder
constexpr long WB_FS = 0;        // [w1|w2] transposed: (64+128)x32 = 6144
constexpr long WB_E1 = 6144;     // 128x128 -> 22528
constexpr long WB_E2 = 22528;    // 64x128  -> 30720
constexpr long WB_GI = 30720;    // 384x192 -> 104448
constexpr long WB_GH = 104448;   // 384x128 -> 153600

using bf8      = __attribute__((ext_vector_type(8))) short;
using f32x4v   = __attribute__((ext_vector_type(4))) float;
using ushort8v = __attribute__((ext_vector_type(8))) unsigned short;

__device__ __forceinline__ unsigned short f2bf(float x) {
    unsigned u = __float_as_uint(x);
    u += 0x7FFFu + ((u >> 16) & 1u);
    return (unsigned short)(u >> 16);
}
__device__ __forceinline__ float bf2f(unsigned short u) {
    return __uint_as_float(((unsigned)u) << 16);
}

__global__ void fill_u32_k(unsigned* __restrict__ p, unsigned v, int n) {
    int i = blockIdx.x * blockDim.x + threadIdx.x;
    if (i < n) p[i] = v;
}

// ---------------- CSR build: count+rank (one atomic per edge, both graphs) ----------------
__global__ void count_rank_k(const int* __restrict__ gdst, unsigned* __restrict__ gcnt,
                             unsigned* __restrict__ grank,
                             const int* __restrict__ cdst, unsigned* __restrict__ ccnt,
                             unsigned* __restrict__ crank) {
    int i = blockIdx.x * blockDim.x + threadIdx.x;
    if (i < E_GT) {
        grank[i] = atomicAdd(gcnt + gdst[i], 1u);
    } else if (i < E_GT + E_COMM) {
        int j = i - E_GT;
        crank[j] = atomicAdd(ccnt + cdst[j], 1u);
    }
}

// exclusive scan of both cnt arrays (block 0: gt, block 1: comm + dinv)
__global__ __launch_bounds__(1024) void scan2_k(const unsigned* __restrict__ cnt0,
                                                unsigned* __restrict__ offs0,
                                                const unsigned* __restrict__ cnt1,
                                                unsigned* __restrict__ offs1,
                                                float* __restrict__ dinv, int n) {
    __shared__ unsigned part[1024];
    const unsigned* cnt = blockIdx.x ? cnt1 : cnt0;
    unsigned* offs = blockIdx.x ? offs1 : offs0;
    int t = threadIdx.x;
    int chunk = (n + 1023) / 1024;
    int b = t * chunk, e = min(n, b + chunk);
    unsigned s = 0;
    for (int i = b; i < e; ++i) s += cnt[i];
    part[t] = s;
    __syncthreads();
    for (int off = 1; off < 1024; off <<= 1) {
        unsigned v = (t >= off) ? part[t - off] : 0u;
        __syncthreads();
        part[t] += v;
        __syncthreads();
    }
    unsigned run = (t > 0) ? part[t - 1] : 0u;
    for (int i = b; i < e; ++i) {
        offs[i] = run;
        if (blockIdx.x) dinv[i] = 1.0f / fmaxf((float)cnt[i], 1.0f);
        run += cnt[i];
    }
    if (t == 1023) offs[n] = run;
}

// atomic-free placement using precomputed ranks (both graphs)
__global__ void place2_k(const int* __restrict__ gsrc, const int* __restrict__ gdst,
                         const unsigned* __restrict__ grank, const unsigned* __restrict__ goffs,
                         unsigned* __restrict__ gsort,
                         const int* __restrict__ csrc, const int* __restrict__ cdst,
                         const unsigned* __restrict__ crank, const unsigned* __restrict__ coffs,
                         unsigned* __restrict__ csort) {
    int i = blockIdx.x * blockDim.x + threadIdx.x;
    if (i < E_GT) {
        gsort[goffs[gdst[i]] + grank[i]] = (unsigned)gsrc[i];
    } else if (i < E_GT + E_COMM) {
        int j = i - E_GT;
        csort[coffs[cdst[j]] + crank[j]] = (unsigned)csrc[j];
    }
}

// ---------------- all weight converts+transposes in one kernel ----------------
__global__ void wconv_all_k(const float* __restrict__ w1, const float* __restrict__ w2,
                            const float* __restrict__ e1, const float* __restrict__ e2,
                            const float* __restrict__ gi, const float* __restrict__ gh,
                            unsigned short* __restrict__ wb) {
    int i = blockIdx.x * blockDim.x + threadIdx.x;
    if (i >= 153600) return;
    const float* W; int K, N; long local;
    if (i < 2048)        { W = w1; K = 32;  N = 64;  local = i; }
    else if (i < 6144)   { W = w2; K = 32;  N = 128; local = i - 2048; }
    else if (i < 22528)  { W = e1; K = 128; N = 128; local = i - 6144; }
    else if (i < 30720)  { W = e2; K = 128; N = 64;  local = i - 22528; }
    else if (i < 104448) { W = gi; K = 192; N = 384; local = i - 30720; }
    else                 { W = gh; K = 128; N = 384; local = i - 104448; }
    long n = local / K, k = local - n * K;
    wb[i] = f2bf(W[k * N + n]);
}

// ---------------- all attention projection vectors in one kernel ----------------
__global__ void make_v_all_k(const float* __restrict__ w1s, const float* __restrict__ a1l,
                             const float* __restrict__ w1d, const float* __restrict__ a1r,
                             const float* __restrict__ w2s, const float* __restrict__ a2l,
                             const float* __restrict__ w2d, const float* __restrict__ a2r,
                             float* __restrict__ v) {
    int i = blockIdx.x * blockDim.x + threadIdx.x;
    if (i >= 1024) return;
    const float *w, *a; int dh, local;
    if (i < 128)      { w = w1s; a = a1l; dh = 16; local = i; }
    else if (i < 384) { w = w1d; a = a1r; dh = 16; local = i - 128; }
    else if (i < 512) { w = w2s; a = a2l; dh = 32; local = i - 384; }
    else              { w = w2d; a = a2r; dh = 32; local = i - 512; }
    int k = local >> 2, h = local & 3;
    float s = 0.f;
    for (int j = 0; j < dh; ++j) s += w[k * (4 * dh) + h * dh + j] * a[h * dh + j];
    v[i] = s;
}

// ---------------- el1/el2 (feat_gt) + er1 (feat_agent) in one kernel ----------------
__global__ void rowvec_all_k(const float* __restrict__ fgt, const float* __restrict__ fag,
                             const float* __restrict__ v1, const float* __restrict__ v2,
                             const float* __restrict__ vr1,
                             float* __restrict__ el1, float* __restrict__ el2,
                             float* __restrict__ er1) {
    int i = blockIdx.x * blockDim.x + threadIdx.x;
    if (i < N_GT) {
        float a[8] = {};
        const float* fp = fgt + (long)i * 32;
        for (int k = 0; k < 32; ++k) {
            float x = fp[k];
#pragma unroll
            for (int j = 0; j < 4; ++j) a[j] += x * v1[4 * k + j];
#pragma unroll
            for (int j = 0; j < 4; ++j) a[4 + j] += x * v2[4 * k + j];
        }
        *reinterpret_cast<float4*>(el1 + 4l * i) = {a[0], a[1], a[2], a[3]};
        *reinterpret_cast<float4*>(el2 + 4l * i) = {a[4], a[5], a[6], a[7]};
    } else if (i < N_GT + N_AG) {
        int r = i - N_GT;
        float a0 = 0, a1 = 0, a2 = 0, a3 = 0;
        const float* fp = fag + (long)r * 64;
        for (int k = 0; k < 64; ++k) {
            float x = fp[k];
            a0 += x * vr1[4 * k]; a1 += x * vr1[4 * k + 1];
            a2 += x * vr1[4 * k + 2]; a3 += x * vr1[4 * k + 3];
        }
        *reinterpret_cast<float4*>(er1 + 4l * r) = {a0, a1, a2, a3};
    }
}

__global__ void rowvec2_k(const float* __restrict__ f1, const float* __restrict__ f2,
                          const float* __restrict__ v, float* __restrict__ out, int n, int K1, int K2) {
    int i = blockIdx.x * blockDim.x + threadIdx.x;
    if (i >= n) return;
    float a0 = 0, a1 = 0, a2 = 0, a3 = 0;
    const float* fp = f1 + (long)i * K1;
    for (int k = 0; k < K1; ++k) {
        float x = fp[k];
        a0 += x * v[4 * k]; a1 += x * v[4 * k + 1];
        a2 += x * v[4 * k + 2]; a3 += x * v[4 * k + 3];
    }
    const float* gp = f2 + (long)i * K2;
    const float* v2 = v + 4l * K1;
    for (int k = 0; k < K2; ++k) {
        float x = gp[k];
        a0 += x * v2[4 * k]; a1 += x * v2[4 * k + 1];
        a2 += x * v2[4 * k + 2]; a3 += x * v2[4 * k + 3];
    }
    float4 r = {a0, a1, a2, a3};
    *reinterpret_cast<float4*>(out + 4l * i) = r;
}

// ---------------- bf16 MFMA GEMM ----------------
template <int ACT, int OB>
__global__ __launch_bounds__(256) void mgemm_k(const float* __restrict__ A,
                                               const float* __restrict__ A2, int K1,
                                               const unsigned short* __restrict__ Bt,
                                               const float* __restrict__ bias,
                                               void* __restrict__ Cv,
                                               int M, int N, int K) {
    __shared__ unsigned short As[64][40];
    __shared__ unsigned short Bs[64][40];
    const int tid = threadIdx.x;
    const int lane = tid & 63, wv = tid >> 6;
    const int wm = wv & 1, wn = wv >> 1;
    const int quad = lane >> 4, l16 = lane & 15;
    const int m0 = blockIdx.y * 64, n0 = blockIdx.x * 64;
    const int K2 = K - K1;
    f32x4v acc[2][2] = {};
    const int rA = tid >> 3, cA = (tid & 7) * 4;
    const int rB = tid >> 2, cB = (tid & 3) * 8;

    for (int k0 = 0; k0 < K; k0 += 32) {
#pragma unroll
        for (int half = 0; half < 2; ++half) {
            const int r = rA + half * 32;
            const int row = m0 + r;
            const int kg = k0 + cA;
            float4 v = {0.f, 0.f, 0.f, 0.f};
            if (row < M) {
                v = (kg < K1) ? *reinterpret_cast<const float4*>(A + (long)row * K1 + kg)
                              : *reinterpret_cast<const float4*>(A2 + (long)row * K2 + (kg - K1));
            }
            ushort4 b;
            b.x = f2bf(v.x); b.y = f2bf(v.y); b.z = f2bf(v.z); b.w = f2bf(v.w);
            *reinterpret_cast<ushort4*>(&As[r][cA]) = b;
        }
        *reinterpret_cast<ushort8v*>(&Bs[rB][cB]) =
            *reinterpret_cast<const ushort8v*>(Bt + (long)(n0 + rB) * K + k0 + cB);
        __syncthreads();

        const bf8 a0 = *reinterpret_cast<const bf8*>(&As[wm * 32 + l16][quad * 8]);
        const bf8 a1 = *reinterpret_cast<const bf8*>(&As[wm * 32 + 16 + l16][quad * 8]);
        const bf8 b0 = *reinterpret_cast<const bf8*>(&Bs[wn * 32 + l16][quad * 8]);
        const bf8 b1 = *reinterpret_cast<const bf8*>(&Bs[wn * 32 + 16 + l16][quad * 8]);
        acc[0][0] = __builtin_amdgcn_mfma_f32_16x16x32_bf16(a0, b0, acc[0][0], 0, 0, 0);
        acc[0][1] = __builtin_amdgcn_mfma_f32_16x16x32_bf16(a0, b1, acc[0][1], 0, 0, 0);
        acc[1][0] = __builtin_amdgcn_mfma_f32_16x16x32_bf16(a1, b0, acc[1][0], 0, 0, 0);
        acc[1][1] = __builtin_amdgcn_mfma_f32_16x16x32_bf16(a1, b1, acc[1][1], 0, 0, 0);
        __syncthreads();
    }

#pragma unroll
    for (int mt = 0; mt < 2; ++mt)
#pragma unroll
        for (int nt = 0; nt < 2; ++nt)
#pragma unroll
            for (int r = 0; r < 4; ++r) {
                const int row = m0 + wm * 32 + mt * 16 + quad * 4 + r;
                const int col = n0 + wn * 32 + nt * 16 + l16;
                if (row < M) {
                    float v = acc[mt][nt][r];
                    if (bias) v += bias[col];
                    if (ACT) v = fmaxf(v, 0.f);
                    if (OB) ((unsigned short*)Cv)[(long)row * N + col] = f2bf(v);
                    else    ((float*)Cv)[(long)row * N + col] = v;
                }
            }
}

// ---------------- fused fs1+fs2 producer ----------------
__global__ __launch_bounds__(256) void fs_gemm_k(const float* __restrict__ A,
                                                 const unsigned short* __restrict__ Btc,
                                                 unsigned short* __restrict__ fsb1,
                                                 unsigned short* __restrict__ fsb2, int M) {
    __shared__ unsigned short As[64][40];
    __shared__ unsigned short Bs[64][40];
    const int tid = threadIdx.x;
    const int lane = tid & 63, wv = tid >> 6;
    const int wm = wv & 1, wn = wv >> 1;
    const int quad = lane >> 4, l16 = lane & 15;
    const int m0 = blockIdx.y * 64, n0 = blockIdx.x * 64;
    f32x4v acc[2][2] = {};
    const int rA = tid >> 3, cA = (tid & 7) * 4;
    const int rB = tid >> 2, cB = (tid & 3) * 8;

#pragma unroll
    for (int half = 0; half < 2; ++half) {
        const int r = rA + half * 32;
        const int row = m0 + r;
        float4 v = {0.f, 0.f, 0.f, 0.f};
        if (row < M) v = *reinterpret_cast<const float4*>(A + (long)row * 32 + cA);
        ushort4 b;
        b.x = f2bf(v.x); b.y = f2bf(v.y); b.z = f2bf(v.z); b.w = f2bf(v.w);
        *reinterpret_cast<ushort4*>(&As[r][cA]) = b;
    }
    *reinterpret_cast<ushort8v*>(&Bs[rB][cB]) =
        *reinterpret_cast<const ushort8v*>(Btc + (long)(n0 + rB) * 32 + cB);
    __syncthreads();

    const bf8 a0 = *reinterpret_cast<const bf8*>(&As[wm * 32 + l16][quad * 8]);
    const bf8 a1 = *reinterpret_cast<const bf8*>(&As[wm * 32 + 16 + l16][quad * 8]);
    const bf8 b0 = *reinterpret_cast<const bf8*>(&Bs[wn * 32 + l16][quad * 8]);
    const bf8 b1 = *reinterpret_cast<const bf8*>(&Bs[wn * 32 + 16 + l16][quad * 8]);
    acc[0][0] = __builtin_amdgcn_mfma_f32_16x16x32_bf16(a0, b0, acc[0][0], 0, 0, 0);
    acc[0][1] = __builtin_amdgcn_mfma_f32_16x16x32_bf16(a0, b1, acc[0][1], 0, 0, 0);
    acc[1][0] = __builtin_amdgcn_mfma_f32_16x16x32_bf16(a1, b0, acc[1][0], 0, 0, 0);
    acc[1][1] = __builtin_amdgcn_mfma_f32_16x16x32_bf16(a1, b1, acc[1][1], 0, 0, 0);

#pragma unroll
    for (int mt = 0; mt < 2; ++mt)
#pragma unroll
        for (int nt = 0; nt < 2; ++nt)
#pragma unroll
            for (int r = 0; r < 4; ++r) {
                const int row = m0 + wm * 32 + mt * 16 + quad * 4 + r;
                const int col = n0 + wn * 32 + nt * 16 + l16;
                if (row < M) {
                    unsigned short v16 = f2bf(acc[mt][nt][r]);
                    if (col < 64) fsb1[(long)row * 64 + col] = v16;
                    else          fsb2[(long)row * 128 + (col - 64)] = v16;
                }
            }
}

// ---------------- fused flash GAT: chunked softmax + 16-deep batched gathers (clamped) ----------------
template <int CH>
__global__ __launch_bounds__(256) void gat_fused_k(
    const unsigned* __restrict__ offs, const unsigned* __restrict__ ssrc,
    const float* __restrict__ el, const float* __restrict__ er,
    const unsigned short* __restrict__ fsb,
    const float* __restrict__ res0, const float* __restrict__ res1,
    const float* __restrict__ bias, float* __restrict__ out, int n_dst, unsigned nsrc)
{
    constexpr int CPL = CH / 64;
    const int wid = threadIdx.x >> 6;
    const int lane = threadIdx.x & 63;
    const int d = blockIdx.x * 4 + wid;
    if (d >= n_dst) return;
    const int h = lane >> 4, ei = lane & 15;
    const float er_h = er[4l * d + h];
    const unsigned beg = offs[d], end = offs[d + 1];
    const int c0 = lane * CPL;
    const unsigned smax = nsrc - 1u;
    float m = -INFINITY, s = 0.f, acc0 = 0.f, acc1 = 0.f;

    for (unsigned base = beg; base < end; base += 16) {
        const unsigned na = min(16u, end - base);
        unsigned sv = ssrc[base + ((unsigned)ei < na ? (unsigned)ei : 0u)];
        sv = min(sv, smax);   // safety clamp
        unsigned fw[16];
#pragma unroll
        for (int j = 0; j < 16; ++j) {
            const unsigned sj = (unsigned)__shfl((int)sv, j);
            if (CPL == 2) fw[j] = *reinterpret_cast<const unsigned*>(fsb + (long)sj * CH + c0);
            else          fw[j] = fsb[(long)sj * CH + c0];
        }
        float xv = -INFINITY;
        if ((unsigned)ei < na) {
            float x = el[4l * sv + h] + er_h;
            xv = (x >= 0.f) ? x : LRELU_S * x;
        }
        float cm = xv;
#pragma unroll
        for (int off = 1; off < 16; off <<= 1) cm = fmaxf(cm, __shfl_xor(cm, off));
        const float mn = fmaxf(m, cm);
        const float corr = __expf(m - mn);
        const float p = __expf(xv - mn);
        float ps = p;
#pragma unroll
        for (int off = 1; off < 16; off <<= 1) ps += __shfl_xor(ps, off);
        s = s * corr + ps;
        acc0 *= corr; acc1 *= corr;
        m = mn;
#pragma unroll
        for (int j = 0; j < 16; ++j) {
            const float pj = __shfl(p, (h << 4) | j);
            if (CPL == 2) {
                acc0 += pj * __uint_as_float((fw[j] & 0xFFFFu) << 16);
                acc1 += pj * __uint_as_float((fw[j] >> 16) << 16);
            } else {
                acc0 += pj * bf2f((unsigned short)fw[j]);
            }
        }
    }
    const float inv = (s > 0.f) ? 1.f / s : 0.f;
    if (CPL == 1) {
        float r = res0[(long)d * 64 + c0];
        out[(long)d * 64 + c0] = fmaxf(acc0 * inv + r + bias[c0], 0.f);
    } else {
        float2 r = (c0 < 64) ? *reinterpret_cast<const float2*>(res0 + (long)d * 64 + c0)
                             : *reinterpret_cast<const float2*>(res1 + (long)d * 64 + (c0 - 64));
        float2 o;
        o.x = fmaxf(acc0 * inv + r.x + bias[c0], 0.f);
        o.y = fmaxf(acc1 * inv + r.y + bias[c0 + 1], 0.f);
        *reinterpret_cast<float2*>(out + (long)d * 128 + c0) = o;
    }
}

// ---------------- comm mailbox mean: 16-deep batched gathers (clamped) ----------------
__global__ __launch_bounds__(256) void comm_gather_k(const unsigned* __restrict__ offs,
                                                     const unsigned* __restrict__ ssrc,
                                                     const unsigned short* __restrict__ mb,
                                                     const float* __restrict__ dinv,
                                                     float* __restrict__ y, int n) {
    const int wid = threadIdx.x >> 6;
    const int lane = threadIdx.x & 63;
    const int d = blockIdx.x * 4 + wid;
    if (d >= n) return;
    const unsigned beg = offs[d], end = offs[d + 1];
    const int ei = lane & 15;
    const unsigned smax = (unsigned)n - 1u;
    float acc = 0.f;
    for (unsigned base = beg; base < end; base += 16) {
        const unsigned na = min(16u, end - base);
        unsigned sv = ssrc[base + ((unsigned)ei < na ? (unsigned)ei : 0u)];
        sv = min(sv, smax);
        unsigned short fw[16];
#pragma unroll
        for (int j = 0; j < 16; ++j) {
            const unsigned sj = (unsigned)__shfl((int)sv, j);
            fw[j] = mb[(long)sj * 64 + lane];
        }
#pragma unroll
        for (int j = 0; j < 16; ++j)
            if ((unsigned)j < na) acc += bf2f(fw[j]);
    }
    y[(long)d * 64 + lane] = acc * dinv[d];
}

// ---------------- GRU pointwise (bf16 gi/gh) ----------------
__global__ void gru_k(const unsigned short* __restrict__ gi, const unsigned short* __restrict__ gh,
                      const float* __restrict__ hprev, float* __restrict__ hout, int n) {
    int i = blockIdx.x * blockDim.x + threadIdx.x;
    if (i >= n) return;
    int row = i >> 7, j = i & 127;
    const unsigned short* gir = gi + (long)row * 384;
    const unsigned short* ghr = gh + (long)row * 384;
    float r  = 1.f / (1.f + __expf(-(bf2f(gir[j]) + bf2f(ghr[j]))));
    float zg = 1.f / (1.f + __expf(-(bf2f(gir[j + 128]) + bf2f(ghr[j + 128]))));
    float nn = tanhf(bf2f(gir[j + 256]) + r * bf2f(ghr[j + 256]));
    hout[i] = (1.f - zg) * nn + zg * hprev[i];
}

// ---------------- output: h@out_w+out_b  followed by copy of h ----------------
__global__ void outcopy_k(const float* __restrict__ h, const float* __restrict__ w,
                          const float* __restrict__ b, float* __restrict__ out) {
    int i = blockIdx.x * blockDim.x + threadIdx.x;
    if (i >= N_AG * 128) return;
    out[(long)N_AG * OUTD + i] = h[i];
    if (i < N_AG) {
        float acc[OUTD];
#pragma unroll
        for (int j = 0; j < OUTD; ++j) acc[j] = b[j];
        for (int k = 0; k < 128; ++k) {
            float v = h[(long)i * 128 + k];
#pragma unroll
            for (int j = 0; j < OUTD; ++j) acc[j] += v * w[k * OUTD + j];
        }
#pragma unroll
        for (int j = 0; j < OUTD; ++j) out[(long)i * OUTD + j] = acc[j];
    }
}

// ---------------- launcher ----------------
extern "C" void kernel_launch(void* const* d_in, const int* in_sizes, int n_in,
                              void* d_out, int out_size, void* d_ws, size_t ws_size,
                              hipStream_t stream) {
    const float* feat_gt    = (const float*)d_in[0];
    const float* feat_agent = (const float*)d_in[1];
    const float* z_in       = (const float*)d_in[2];
    const int*   gt_src     = (const int*)d_in[3];
    const int*   gt_dst     = (const int*)d_in[4];
    const int*   comm_src   = (const int*)d_in[5];
    const int*   comm_dst   = (const int*)d_in[6];
    const float* w1_src = (const float*)d_in[7];
    const float* w1_dst = (const float*)d_in[8];
    const float* a1_l   = (const float*)d_in[9];
    const float* a1_r   = (const float*)d_in[10];
    const float* b1     = (const float*)d_in[11];
    const float* w2_src = (const float*)d_in[12];
    const float* w2_dst = (const float*)d_in[13];
    const float* a2_l   = (const float*)d_in[14];
    const float* a2_r   = (const float*)d_in[15];
    const float* b2     = (const float*)d_in[16];
    const float* enc_w1 = (const float*)d_in[17];
    const float* enc_b1 = (const float*)d_in[18];
    const float* enc_w2 = (const float*)d_in[19];
    const float* enc_b2 = (const float*)d_in[20];
    const float* gw_ih  = (const float*)d_in[21];
    const float* gw_hh  = (const float*)d_in[22];
    const float* gb_ih  = (const float*)d_in[23];
    const float* gb_hh  = (const float*)d_in[24];
    const float* out_w  = (const float*)d_in[25];
    const float* out_b  = (const float*)d_in[26];

    float* ws = (float*)d_ws;
    unsigned* wsu = (unsigned*)d_ws;
    unsigned short* wb = (unsigned short*)(ws + O_WB);
    float* out = (float*)d_out;

    auto blk = [](long n) { return dim3((unsigned)((n + 255) / 256)); };
    const dim3 T(256);

    // ---------- CSR build (both graphs, 4 kernels, atomic-free placement) ----------
    fill_u32_k<<<blk(40000), T, 0, stream>>>(wsu + O_CNT_GT, 0u, 40000);  // CNT_GT + CNT_CM contiguous
    count_rank_k<<<blk(E_GT + E_COMM), T, 0, stream>>>(gt_dst, wsu + O_CNT_GT, wsu + O_RANK_GT,
                                                       comm_dst, wsu + O_CNT_CM, wsu + O_RANK_CM);
    scan2_k<<<2, 1024, 0, stream>>>(wsu + O_CNT_GT, wsu + O_OFFS_GT,
                                    wsu + O_CNT_CM, wsu + O_OFFS_CM, ws + O_DINV, N_AG);
    place2_k<<<blk(E_GT + E_COMM), T, 0, stream>>>(gt_src, gt_dst, wsu + O_RANK_GT, wsu + O_OFFS_GT, wsu + O_SRT_GT,
                                                   comm_src, comm_dst, wsu + O_RANK_CM, wsu + O_OFFS_CM, wsu + O_SRT_CM);

    // ---------- weights + attention vectors + el/er ----------
    wconv_all_k<<<blk(153600), T, 0, stream>>>(w1_src, w2_src, enc_w1, enc_w2, gw_ih, gw_hh, wb);
    make_v_all_k<<<4, 256, 0, stream>>>(w1_src, a1_l, w1_dst, a1_r, w2_src, a2_l, w2_dst, a2_r, ws + O_V);
    float* VL1 = ws + O_V, *VR1 = ws + O_V + 128, *VL2 = ws + O_V + 384, *VR2 = ws + O_V + 512;
    rowvec_all_k<<<blk(N_GT + N_AG), T, 0, stream>>>(feat_gt, feat_agent, VL1, VL2, VR1,
                                                     ws + O_EL1, ws + O_EL2, ws + O_ER1);

    const int MB_GT = (N_GT + 63) / 64, MB_AG = (N_AG + 63) / 64;
    unsigned short* fsb1 = (unsigned short*)(ws + O_FSB1);
    unsigned short* fsb2 = (unsigned short*)(ws + O_FSB2);

    // ---------- fused fs1+fs2 producer ----------
    fs_gemm_k<<<dim3(3, MB_GT), T, 0, stream>>>(feat_gt, wb + WB_FS, fsb1, fsb2, N_GT);

    // ---------- GAT1 ----------
    gat_fused_k<64><<<dim3((N_AG + 3) / 4), T, 0, stream>>>(wsu + O_OFFS_GT, wsu + O_SRT_GT,
        ws + O_EL1, ws + O_ER1, fsb1, feat_agent, nullptr, b1, ws + O_RST1, N_AG, N_GT);

    // ---------- GAT2 ----------
    rowvec2_k<<<blk(N_AG), T, 0, stream>>>(ws + O_RST1, feat_agent, VR2, ws + O_ER2, N_AG, 64, 64);
    gat_fused_k<128><<<dim3((N_AG + 3) / 4), T, 0, stream>>>(wsu + O_OFFS_GT, wsu + O_SRT_GT,
        ws + O_EL2, ws + O_ER2, fsb2, ws + O_RST1, feat_agent, b2, ws + O_RST2, N_AG, N_GT);

    // ---------- comm steps ----------
    float* h = ws + O_RST2;
    unsigned short* mb = (unsigned short*)(ws + O_M);
    unsigned short* gib = (unsigned short*)(ws + O_GI);
    unsigned short* ghb = (unsigned short*)(ws + O_GH);
    for (int step = 0; step < 2; ++step) {
        const float* zz = (step == 0) ? z_in : h;
        mgemm_k<1, 0><<<dim3(2, MB_AG), T, 0, stream>>>(h, nullptr, 128, wb + WB_E1, enc_b1, ws + O_T1, N_AG, 128, 128);
        mgemm_k<1, 1><<<dim3(1, MB_AG), T, 0, stream>>>(ws + O_T1, nullptr, 128, wb + WB_E2, enc_b2, mb, N_AG, 64, 128);
        comm_gather_k<<<dim3((N_AG + 3) / 4), T, 0, stream>>>(wsu + O_OFFS_CM, wsu + O_SRT_CM,
            mb, ws + O_DINV, ws + O_Y, N_AG);
        mgemm_k<0, 1><<<dim3(6, MB_AG), T, 0, stream>>>(h, ws + O_Y, 128, wb + WB_GI, gb_ih, gib, N_AG, 384, 192);
        mgemm_k<0, 1><<<dim3(6, MB_AG), T, 0, stream>>>(zz, nullptr, 128, wb + WB_GH, gb_hh, ghb, N_AG, 384, 128);
        gru_k<<<blk((long)N_AG * 128), T, 0, stream>>>(gib, ghb, zz, h, N_AG * 128);
    }

    // ---------- outputs ----------
    outcopy_k<<<blk((long)N_AG * 128), T, 0, stream>>>(h, out_w, out_b, out);
}